// Round 1
// baseline (378.541 us; speedup 1.0000x reference)
//
#include <hip/hip_runtime.h>
#include <math.h>

#define NEG_SLOPE 0.2f
#define GEPS 1e-5f

typedef __attribute__((ext_vector_type(8))) short short8;
typedef __attribute__((ext_vector_type(4))) float floatx4;

__device__ __forceinline__ float wave_reduce_sum(float v) {
#pragma unroll
    for (int o = 32; o > 0; o >>= 1) v += __shfl_down(v, o);
    return v;
}

__device__ __forceinline__ ushort f2bf(float f) {
    union { float f; unsigned int i; } c;
    c.f = f;
    unsigned int b = c.i;
    b += 0x7fffu + ((b >> 16) & 1u);
    return (ushort)(b >> 16);
}

__device__ __forceinline__ float bf2f(ushort u) {
    union { unsigned int i; float f; } c;
    c.i = (unsigned int)u << 16;
    return c.f;
}

__device__ __forceinline__ float2 unpack_bf2(unsigned int u) {
    union { unsigned int i; float f; } a, b;
    a.i = u << 16;            // low ushort -> even col
    b.i = u & 0xffff0000u;    // high ushort -> odd col
    return make_float2(a.f, b.f);
}

__device__ __forceinline__ unsigned int pack_bf2(float lo, float hi) {
    return (unsigned int)f2bf(lo) | ((unsigned int)f2bf(hi) << 16);
}

__device__ __forceinline__ float lrelu(float v) {
    return (v > 0.f) ? v : v * NEG_SLOPE;
}

__device__ __forceinline__ float elu_fast(float v) {
    return (v > 0.f) ? v : (__expf(v) - 1.f);
}

// ---------------- merged prologue: layer-1 transform + W2 frag + attn consts + ea/deg ----
// blocks [0, NB1)            : layer-1 transform, 2 nodes/block
// blocks [NB1, NB1+16)       : W2 -> bf16 MFMA B-fragment layout
// block  NB1+16              : C1/C2 attention constants
// blocks [NB1+17, NB1+17+256): edge_attr column sums + degree histogram
__global__ __launch_bounds__(256) void k_pre(
    const float* __restrict__ x, const float* __restrict__ W1,
    const float* __restrict__ as1, const float* __restrict__ ad1,
    const float* __restrict__ ea, const int* __restrict__ dst,
    const float* __restrict__ W2, const float* __restrict__ We1,
    const float* __restrict__ ae1, const float* __restrict__ We2,
    const float* __restrict__ ae2,
    ushort* __restrict__ h1, float* __restrict__ al_s, float* __restrict__ al_d,
    float* __restrict__ ea_sum, int* __restrict__ deg, uint4* __restrict__ Bfrag,
    float* __restrict__ C1, float* __restrict__ C2, int N, int E, int NB1) {
    int b = blockIdx.x;
    if (b < NB1) {
        int u = threadIdx.x >> 7;
        int n = b * 2 + u;
        if (n >= N) return;
        int t = threadIdx.x & 127, lane = threadIdx.x & 63;
        int c0 = 2 * t;
        float x0 = x[3 * n], x1 = x[3 * n + 1], x2 = x[3 * n + 2];
        float h0 = fmaf(x0, W1[c0], fmaf(x1, W1[256 + c0], x2 * W1[512 + c0]));
        float h1v = fmaf(x0, W1[c0 + 1], fmaf(x1, W1[257 + c0], x2 * W1[513 + c0]));
        ((unsigned int*)h1)[(size_t)n * 128 + t] = pack_bf2(h0, h1v);
        float ps = h0 * as1[c0] + h1v * as1[c0 + 1];
        float pd = h0 * ad1[c0] + h1v * ad1[c0 + 1];
#pragma unroll
        for (int o = 16; o > 0; o >>= 1) {
            ps += __shfl_xor(ps, o);
            pd += __shfl_xor(pd, o);
        }
        if ((lane & 31) == 0) {
            int h = c0 >> 6;
            al_s[n * 4 + h] = ps;
            al_d[n * 4 + h] = pd;
        }
        return;
    }
    b -= NB1;
    if (b < 16) {
        int t = b * 256 + threadIdx.x;  // 4096 threads
        int c = t >> 9, kk = (t >> 6) & 7, L = t & 63;
        int q = L >> 4, n = c * 16 + (L & 15);
        int k0 = kk * 32 + q * 8;
        unsigned int u0 = pack_bf2(W2[(k0 + 0) * 128 + n], W2[(k0 + 1) * 128 + n]);
        unsigned int u1 = pack_bf2(W2[(k0 + 2) * 128 + n], W2[(k0 + 3) * 128 + n]);
        unsigned int u2 = pack_bf2(W2[(k0 + 4) * 128 + n], W2[(k0 + 5) * 128 + n]);
        unsigned int u3 = pack_bf2(W2[(k0 + 6) * 128 + n], W2[(k0 + 7) * 128 + n]);
        Bfrag[t] = make_uint4(u0, u1, u2, u3);
        return;
    }
    if (b == 16) {
        int t = threadIdx.x, h = t >> 6, lane = t & 63;
        float p0 = We1[t] * ae1[t];
        float p1 = We1[256 + t] * ae1[t];
        p0 = wave_reduce_sum(p0);
        p1 = wave_reduce_sum(p1);
        if (lane == 0) { C1[h] = p0; C1[4 + h] = p1; }
        if (t < 128) {
            float q0 = We2[t] * ae2[t];
            float q1 = We2[128 + t] * ae2[t];
            q0 = wave_reduce_sum(q0);
            q1 = wave_reduce_sum(q1);
            if (lane == 0) { C2[h] = q0; C2[2 + h] = q1; }
        }
        return;
    }
    b -= 17;
    const float2* ea2 = (const float2*)ea;
    float s0 = 0.f, s1 = 0.f;
    for (int e = b * 256 + threadIdx.x; e < E; e += 256 * 256) {
        float2 v = ea2[e];
        s0 += v.x; s1 += v.y;
        atomicAdd(&deg[dst[e]], 1);
    }
    s0 = wave_reduce_sum(s0);
    s1 = wave_reduce_sum(s1);
    if ((threadIdx.x & 63) == 0) {
        atomicAdd(&ea_sum[0], s0);
        atomicAdd(&ea_sum[1], s1);
    }
}

// ---------------- CSR row_ptr scan (block-local) ----------------
__global__ void k_scan1(const int* __restrict__ deg, int* __restrict__ row_ptr,
                        int* __restrict__ bsum, int N) {
    __shared__ int tmp[1024];
    int tid = threadIdx.x;
    int i = blockIdx.x * 1024 + tid;
    int v = (i < N) ? deg[i] : 0;
    tmp[tid] = v;
    __syncthreads();
#pragma unroll
    for (int off = 1; off < 1024; off <<= 1) {
        int t = (tid >= off) ? tmp[tid - off] : 0;
        __syncthreads();
        tmp[tid] += t;
        __syncthreads();
    }
    if (i < N) row_ptr[i + 1] = tmp[tid];
    if (tid == 1023) bsum[blockIdx.x] = tmp[1023];
}

// block prefix recomputed per block in one wave (nb1 <= 64), then applied.
// also computes the self-loop attention constants lE1/lE2 (needs ea_sum from k_pre).
__global__ void k_scan23(int* __restrict__ row_ptr, const int* __restrict__ bsum,
                         const float* __restrict__ ea_sum, const float* __restrict__ C1,
                         const float* __restrict__ C2, float* __restrict__ lE1,
                         float* __restrict__ lE2, int N, int E) {
    __shared__ int off_s;
    int t = threadIdx.x;
    if (blockIdx.x == 0 && t >= 64 && t < 68) {
        int k = t - 64;
        float m0 = ea_sum[0] / (float)E, m1 = ea_sum[1] / (float)E;
        lE1[k] = m0 * C1[k] + m1 * C1[4 + k];
        if (k < 2) lE2[k] = m0 * C2[k] + m1 * C2[2 + k];
    }
    if (t < 64) {
        int v = (t < blockIdx.x) ? bsum[t] : 0;
#pragma unroll
        for (int o = 32; o > 0; o >>= 1) v += __shfl_xor(v, o);
        if (t == 0) off_s = v;
    }
    __syncthreads();
    int off = off_s;
    int i = blockIdx.x * 1024 + t;
    if (i == 0) row_ptr[0] = 0;
    if (i < N) row_ptr[i + 1] += off;
}

// ---------------- CSR scatter: edg[slot] = {src, ea.x, ea.y} ----------------
// slot via atomicSub on deg (deg is dead after the scan; saves the cursor array+memset)
__global__ void k_scat(const int* __restrict__ dst, const int* __restrict__ src,
                       const float* __restrict__ ea, const int* __restrict__ row_ptr,
                       int* __restrict__ deg, float4* __restrict__ edg, int E) {
    int e = blockIdx.x * 256 + threadIdx.x;
    if (e >= E) return;
    int d = dst[e];
    int r = atomicSub(&deg[d], 1);
    int slot = row_ptr[d] + r - 1;
    float2 v = ((const float2*)ea)[e];
    edg[slot] = make_float4(__int_as_float(src[e]), v.x, v.y, 0.f);
}

// ---------------- layer-1 aggregation: inline edge weights + fused GraphNorm stats ------
// grid-strided (2048 blocks); one wave per node per step; 2 edge-groups of 32 lanes.
__global__ __launch_bounds__(256) void k_agg1(const ushort* __restrict__ h1,
                                              const int* __restrict__ row_ptr,
                                              const float4* __restrict__ edg,
                                              const float* __restrict__ al_s,
                                              const float* __restrict__ al_d,
                                              const float* __restrict__ C1,
                                              const float* __restrict__ lE,
                                              const float* __restrict__ bias,
                                              ushort* __restrict__ out,
                                              float* __restrict__ stats, int N) {
    int lane = threadIdx.x & 63;
    int wv = threadIdx.x >> 6;
    int g = lane >> 5, c32 = lane & 31;
    int h = c32 >> 3;
    const uint4* h1u4 = (const uint4*)h1;
    float4 le = *(const float4*)lE;
    float4 c1lo = *(const float4*)C1;
    float4 c1hi = *(const float4*)(C1 + 4);
    float c1h = (h == 0) ? c1lo.x : (h == 1) ? c1lo.y : (h == 2) ? c1lo.z : c1lo.w;
    float c1h4 = (h == 0) ? c1hi.x : (h == 1) ? c1hi.y : (h == 2) ? c1hi.z : c1hi.w;
    float leh = (h == 0) ? le.x : (h == 1) ? le.y : (h == 2) ? le.z : le.w;
    const float* bp = bias + c32 * 8;
    float4 b0 = *(const float4*)bp;
    float4 b1 = *(const float4*)(bp + 4);
    float bb[8] = {b0.x, b0.y, b0.z, b0.w, b1.x, b1.y, b1.z, b1.w};
    float s8[8] = {0.f, 0.f, 0.f, 0.f, 0.f, 0.f, 0.f, 0.f};
    float q8[8] = {0.f, 0.f, 0.f, 0.f, 0.f, 0.f, 0.f, 0.f};
    int stride = gridDim.x << 2;
    for (int n = (blockIdx.x << 2) + wv; n < N; n += stride) {
        float4 adn = *(const float4*)(al_d + 4 * (size_t)n);
        float adh = (h == 0) ? adn.x : (h == 1) ? adn.y : (h == 2) ? adn.z : adn.w;
        float4 asn = *(const float4*)(al_s + 4 * (size_t)n);
        float ash = (h == 0) ? asn.x : (h == 1) ? asn.y : (h == 2) ? asn.z : asn.w;
        uint4 hs = h1u4[(size_t)n * 32 + c32];
        float wself = (g == 0) ? __expf(lrelu(ash + adh + leh)) : 0.f;
        float dsum = wself;
        float acc[8];
        {
            float2 t0 = unpack_bf2(hs.x), t1 = unpack_bf2(hs.y);
            float2 t2 = unpack_bf2(hs.z), t3 = unpack_bf2(hs.w);
            acc[0] = wself * t0.x; acc[1] = wself * t0.y;
            acc[2] = wself * t1.x; acc[3] = wself * t1.y;
            acc[4] = wself * t2.x; acc[5] = wself * t2.y;
            acc[6] = wself * t3.x; acc[7] = wself * t3.y;
        }
        int i0 = row_ptr[n];
        int cnt = row_ptr[n + 1] - i0;
        if (cnt > 0) {
            int last = cnt - 1;
            int j0 = g; float m0 = 1.f;
            if (j0 > last) { j0 = last; m0 = 0.f; }
            int j1 = 2 + g; float m1 = 1.f;
            if (j1 > last) { j1 = last; m1 = 0.f; }
            float4 mA = edg[i0 + j0];
            int sA = __float_as_int(mA.x);
            float4 aA = *(const float4*)(al_s + 4 * (size_t)sA);
            uint4 gvA = h1u4[(size_t)sA * 32 + c32];
            float4 mB = edg[i0 + j1];
            float mkA = m0, mkB = m1;
            int nit = (cnt + 1) >> 1;
            for (int it = 1; it < nit; ++it) {
                int sB = __float_as_int(mB.x);
                float4 aB = *(const float4*)(al_s + 4 * (size_t)sB);
                uint4 gvB = h1u4[(size_t)sB * 32 + c32];
                int jn = 2 * (it + 1) + g;
                float mn = 1.f;
                if (jn > last) { jn = last; mn = 0.f; }
                float4 mC = edg[i0 + jn];
                float av = (h == 0) ? aA.x : (h == 1) ? aA.y : (h == 2) ? aA.z : aA.w;
                float wg = __expf(lrelu(av + adh + mA.y * c1h + mA.z * c1h4)) * mkA;
                dsum += wg;
                float2 u;
                u = unpack_bf2(gvA.x); acc[0] = fmaf(wg, u.x, acc[0]); acc[1] = fmaf(wg, u.y, acc[1]);
                u = unpack_bf2(gvA.y); acc[2] = fmaf(wg, u.x, acc[2]); acc[3] = fmaf(wg, u.y, acc[3]);
                u = unpack_bf2(gvA.z); acc[4] = fmaf(wg, u.x, acc[4]); acc[5] = fmaf(wg, u.y, acc[5]);
                u = unpack_bf2(gvA.w); acc[6] = fmaf(wg, u.x, acc[6]); acc[7] = fmaf(wg, u.y, acc[7]);
                mA = mB; aA = aB; gvA = gvB; mB = mC; mkA = mkB; mkB = mn;
            }
            float av = (h == 0) ? aA.x : (h == 1) ? aA.y : (h == 2) ? aA.z : aA.w;
            float wg = __expf(lrelu(av + adh + mA.y * c1h + mA.z * c1h4)) * mkA;
            dsum += wg;
            float2 u;
            u = unpack_bf2(gvA.x); acc[0] = fmaf(wg, u.x, acc[0]); acc[1] = fmaf(wg, u.y, acc[1]);
            u = unpack_bf2(gvA.y); acc[2] = fmaf(wg, u.x, acc[2]); acc[3] = fmaf(wg, u.y, acc[3]);
            u = unpack_bf2(gvA.z); acc[4] = fmaf(wg, u.x, acc[4]); acc[5] = fmaf(wg, u.y, acc[5]);
            u = unpack_bf2(gvA.w); acc[6] = fmaf(wg, u.x, acc[6]); acc[7] = fmaf(wg, u.y, acc[7]);
        }
#pragma unroll
        for (int k = 0; k < 8; ++k) acc[k] += __shfl_xor(acc[k], 32);
        dsum += __shfl_xor(dsum, 32);
        if (g == 0) {
            float inv = 1.f / dsum;
            unsigned int ow[4];
#pragma unroll
            for (int k = 0; k < 4; ++k) {
                float va = fmaf(acc[2 * k], inv, bb[2 * k]);
                float vb = fmaf(acc[2 * k + 1], inv, bb[2 * k + 1]);
                ushort ua = f2bf(va), ub = f2bf(vb);
                float ra = bf2f(ua), rb = bf2f(ub);
                s8[2 * k] += ra;         q8[2 * k] = fmaf(ra, ra, q8[2 * k]);
                s8[2 * k + 1] += rb;     q8[2 * k + 1] = fmaf(rb, rb, q8[2 * k + 1]);
                ow[k] = (unsigned int)ua | ((unsigned int)ub << 16);
            }
            uint4 o; o.x = ow[0]; o.y = ow[1]; o.z = ow[2]; o.w = ow[3];
            ((uint4*)out)[(size_t)n * 32 + c32] = o;
        }
    }
    // block-level stats reduction: col = c32*8+k, stats[c] = sum, stats[256+c] = sumsq
    __shared__ float red[4 * 32 * 16];
    if (g == 0) {
#pragma unroll
        for (int k = 0; k < 8; ++k) {
            red[(wv * 32 + c32) * 16 + k] = s8[k];
            red[(wv * 32 + c32) * 16 + 8 + k] = q8[k];
        }
    }
    __syncthreads();
    int t = threadIdx.x;
    {
        int cr = t >> 3, k = t & 7;
        float ss = red[(0 * 32 + cr) * 16 + k] + red[(1 * 32 + cr) * 16 + k] +
                   red[(2 * 32 + cr) * 16 + k] + red[(3 * 32 + cr) * 16 + k];
        float qq = red[(0 * 32 + cr) * 16 + 8 + k] + red[(1 * 32 + cr) * 16 + 8 + k] +
                   red[(2 * 32 + cr) * 16 + 8 + k] + red[(3 * 32 + cr) * 16 + 8 + k];
        atomicAdd(&stats[t], ss);
        atomicAdd(&stats[256 + t], qq);
    }
}

// ---------------- MFMA GEMM2 + per-block coef from stats + fused layer-2 attn dots ----------
__global__ __launch_bounds__(256) void k_gemm2_mfma(const ushort* __restrict__ X,
                                                    const float* __restrict__ stats,
                                                    const float* __restrict__ gw,
                                                    const float* __restrict__ gb,
                                                    const float* __restrict__ gms,
                                                    const uint4* __restrict__ Bfrag,
                                                    const float* __restrict__ as2,
                                                    const float* __restrict__ ad2,
                                                    ushort* __restrict__ H2,
                                                    float* __restrict__ al_s,
                                                    float* __restrict__ al_d, int Nn) {
    __shared__ __align__(16) float ABs[512];
    {
        int t = threadIdx.x;
        float inv = 1.f / (float)Nn;
        float mean = stats[t] * inv;
        float cm = mean * gms[t];
        float var = stats[256 + t] * inv - 2.f * cm * mean + cm * cm;
        float A = gw[t] * rsqrtf(var + GEPS);
        ABs[t] = A;
        ABs[256 + t] = gb[t] - A * cm;
    }
    __syncthreads();
    int wave = threadIdx.x >> 6, lane = threadIdx.x & 63;
    int q = lane >> 4, m = lane & 15;
    int rowbase = blockIdx.x * 64 + wave * 16;
    int row = rowbase + m;
    bool valid = row < Nn;
    const uint4* xr4 = (const uint4*)((const unsigned int*)X + (size_t)row * 128);
    uint4 xa[8];
#pragma unroll
    for (int kk = 0; kk < 8; ++kk) {
        int k0 = kk * 32 + q * 8;
        xa[kk] = valid ? xr4[k0 >> 3] : make_uint4(0, 0, 0, 0);
    }
    union { short8 s; unsigned int u[4]; } af[8];
#pragma unroll
    for (int kk = 0; kk < 8; ++kk) {
        int k0 = kk * 32 + q * 8;
        float2 x01 = unpack_bf2(xa[kk].x);
        float2 x23 = unpack_bf2(xa[kk].y);
        float2 x45 = unpack_bf2(xa[kk].z);
        float2 x67 = unpack_bf2(xa[kk].w);
        float4 a0 = *(const float4*)(ABs + k0);
        float4 a1 = *(const float4*)(ABs + k0 + 4);
        float4 b0 = *(const float4*)(ABs + 256 + k0);
        float4 b1 = *(const float4*)(ABs + 256 + k0 + 4);
        float v0 = elu_fast(fmaf(a0.x, x01.x, b0.x));
        float v1 = elu_fast(fmaf(a0.y, x01.y, b0.y));
        float v2 = elu_fast(fmaf(a0.z, x23.x, b0.z));
        float v3 = elu_fast(fmaf(a0.w, x23.y, b0.w));
        float v4 = elu_fast(fmaf(a1.x, x45.x, b1.x));
        float v5 = elu_fast(fmaf(a1.y, x45.y, b1.y));
        float v6 = elu_fast(fmaf(a1.z, x67.x, b1.z));
        float v7 = elu_fast(fmaf(a1.w, x67.y, b1.w));
        af[kk].u[0] = pack_bf2(v0, v1);
        af[kk].u[1] = pack_bf2(v2, v3);
        af[kk].u[2] = pack_bf2(v4, v5);
        af[kk].u[3] = pack_bf2(v6, v7);
    }
    floatx4 acc[8];
#pragma unroll
    for (int c = 0; c < 8; ++c) acc[c] = (floatx4){0.f, 0.f, 0.f, 0.f};
#pragma unroll
    for (int kk = 0; kk < 8; ++kk) {
        const uint4* bpf = Bfrag + kk * 64 + lane;
#pragma unroll
        for (int c = 0; c < 8; ++c) {
            union { short8 s; uint4 u; } bf;
            bf.u = bpf[c * 8 * 64];
            acc[c] = __builtin_amdgcn_mfma_f32_16x16x32_bf16(af[kk].s, bf.s, acc[c], 0, 0, 0);
        }
    }
    float a_s[8], a_d[8];
#pragma unroll
    for (int c = 0; c < 8; ++c) {
        a_s[c] = as2[c * 16 + m];
        a_d[c] = ad2[c * 16 + m];
    }
#pragma unroll
    for (int r = 0; r < 4; ++r) {
        int orow = rowbase + q * 4 + r;
        bool vr = orow < Nn;
        ushort us[8];
        float s0 = 0.f, s1 = 0.f, d0 = 0.f, d1 = 0.f;
#pragma unroll
        for (int c = 0; c < 8; ++c) {
            us[c] = f2bf(acc[c][r]);
            float v = bf2f(us[c]);
            if (c < 4) {
                s0 = fmaf(v, a_s[c], s0);
                d0 = fmaf(v, a_d[c], d0);
            } else {
                s1 = fmaf(v, a_s[c], s1);
                d1 = fmaf(v, a_d[c], d1);
            }
        }
#pragma unroll
        for (int o = 1; o < 16; o <<= 1) {
            s0 += __shfl_xor(s0, o);
            s1 += __shfl_xor(s1, o);
            d0 += __shfl_xor(d0, o);
            d1 += __shfl_xor(d1, o);
        }
        if (vr) {
            ushort* op = H2 + (size_t)orow * 128 + m;
#pragma unroll
            for (int c = 0; c < 8; ++c) op[c * 16] = us[c];
            if (m == 0) {
                *(float2*)(al_s + 2 * (size_t)orow) = make_float2(s0, s1);
                *(float2*)(al_d + 2 * (size_t)orow) = make_float2(d0, d1);
            }
        }
    }
}

// ---------------- layer-2 aggregation: inline edge weights + fused GraphNorm stats ------
__global__ __launch_bounds__(256) void k_agg2(const ushort* __restrict__ h2,
                                              const int* __restrict__ row_ptr,
                                              const float4* __restrict__ edg,
                                              const float* __restrict__ al_s,
                                              const float* __restrict__ al_d,
                                              const float* __restrict__ C2,
                                              const float* __restrict__ lE,
                                              const float* __restrict__ bias,
                                              ushort* __restrict__ out,
                                              float* __restrict__ stats, int N) {
    int lane = threadIdx.x & 63;
    int wv = threadIdx.x >> 6;
    int g = lane >> 4, c16 = lane & 15;
    bool hi = c16 >= 8;
    const uint4* h2u4 = (const uint4*)h2;
    float2 c2v = *(const float2*)C2;
    float2 c2w = *(const float2*)(C2 + 2);
    float c2h = hi ? c2v.y : c2v.x;
    float c2h4 = hi ? c2w.y : c2w.x;
    float leh = hi ? lE[1] : lE[0];
    const float* bp = bias + c16 * 8;
    float4 b0 = *(const float4*)bp;
    float4 b1 = *(const float4*)(bp + 4);
    float bb[8] = {b0.x, b0.y, b0.z, b0.w, b1.x, b1.y, b1.z, b1.w};
    float s8[8] = {0.f, 0.f, 0.f, 0.f, 0.f, 0.f, 0.f, 0.f};
    float q8[8] = {0.f, 0.f, 0.f, 0.f, 0.f, 0.f, 0.f, 0.f};
    int stride = gridDim.x << 2;
    for (int n = (blockIdx.x << 2) + wv; n < N; n += stride) {
        float2 adn = *(const float2*)(al_d + 2 * (size_t)n);
        float adh = hi ? adn.y : adn.x;
        float2 asn = *(const float2*)(al_s + 2 * (size_t)n);
        float ash = hi ? asn.y : asn.x;
        uint4 hs = h2u4[(size_t)n * 16 + c16];
        float wself = (g == 0) ? __expf(lrelu(ash + adh + leh)) : 0.f;
        float dsum = wself;
        float acc[8];
        {
            float2 t0 = unpack_bf2(hs.x), t1 = unpack_bf2(hs.y);
            float2 t2 = unpack_bf2(hs.z), t3 = unpack_bf2(hs.w);
            acc[0] = wself * t0.x; acc[1] = wself * t0.y;
            acc[2] = wself * t1.x; acc[3] = wself * t1.y;
            acc[4] = wself * t2.x; acc[5] = wself * t2.y;
            acc[6] = wself * t3.x; acc[7] = wself * t3.y;
        }
        int i0 = row_ptr[n];
        int cnt = row_ptr[n + 1] - i0;
        if (cnt > 0) {
            int last = cnt - 1;
            int j0 = g; float m0 = 1.f;
            if (j0 > last) { j0 = last; m0 = 0.f; }
            int j1 = 4 + g; float m1 = 1.f;
            if (j1 > last) { j1 = last; m1 = 0.f; }
            float4 mA = edg[i0 + j0];
            int sA = __float_as_int(mA.x);
            float2 aA = *(const float2*)(al_s + 2 * (size_t)sA);
            uint4 gvA = h2u4[(size_t)sA * 16 + c16];
            float4 mB = edg[i0 + j1];
            float mkA = m0, mkB = m1;
            int nit = (cnt + 3) >> 2;
            for (int it = 1; it < nit; ++it) {
                int sB = __float_as_int(mB.x);
                float2 aB = *(const float2*)(al_s + 2 * (size_t)sB);
                uint4 gvB = h2u4[(size_t)sB * 16 + c16];
                int jn = 4 * (it + 1) + g;
                float mn = 1.f;
                if (jn > last) { jn = last; mn = 0.f; }
                float4 mC = edg[i0 + jn];
                float av = hi ? aA.y : aA.x;
                float wg = __expf(lrelu(av + adh + mA.y * c2h + mA.z * c2h4)) * mkA;
                dsum += wg;
                float2 u;
                u = unpack_bf2(gvA.x); acc[0] = fmaf(wg, u.x, acc[0]); acc[1] = fmaf(wg, u.y, acc[1]);
                u = unpack_bf2(gvA.y); acc[2] = fmaf(wg, u.x, acc[2]); acc[3] = fmaf(wg, u.y, acc[3]);
                u = unpack_bf2(gvA.z); acc[4] = fmaf(wg, u.x, acc[4]); acc[5] = fmaf(wg, u.y, acc[5]);
                u = unpack_bf2(gvA.w); acc[6] = fmaf(wg, u.x, acc[6]); acc[7] = fmaf(wg, u.y, acc[7]);
                mA = mB; aA = aB; gvA = gvB; mB = mC; mkA = mkB; mkB = mn;
            }
            float av = hi ? aA.y : aA.x;
            float wg = __expf(lrelu(av + adh + mA.y * c2h + mA.z * c2h4)) * mkA;
            dsum += wg;
            float2 u;
            u = unpack_bf2(gvA.x); acc[0] = fmaf(wg, u.x, acc[0]); acc[1] = fmaf(wg, u.y, acc[1]);
            u = unpack_bf2(gvA.y); acc[2] = fmaf(wg, u.x, acc[2]); acc[3] = fmaf(wg, u.y, acc[3]);
            u = unpack_bf2(gvA.z); acc[4] = fmaf(wg, u.x, acc[4]); acc[5] = fmaf(wg, u.y, acc[5]);
            u = unpack_bf2(gvA.w); acc[6] = fmaf(wg, u.x, acc[6]); acc[7] = fmaf(wg, u.y, acc[7]);
        }
#pragma unroll
        for (int k = 0; k < 8; ++k) {
            acc[k] += __shfl_xor(acc[k], 16);
            acc[k] += __shfl_xor(acc[k], 32);
        }
        dsum += __shfl_xor(dsum, 16);
        dsum += __shfl_xor(dsum, 32);
        if (g == 0) {
            float inv = 1.f / dsum;
            unsigned int ow[4];
#pragma unroll
            for (int k = 0; k < 4; ++k) {
                float va = fmaf(acc[2 * k], inv, bb[2 * k]);
                float vb = fmaf(acc[2 * k + 1], inv, bb[2 * k + 1]);
                ushort ua = f2bf(va), ub = f2bf(vb);
                float ra = bf2f(ua), rb = bf2f(ub);
                s8[2 * k] += ra;         q8[2 * k] = fmaf(ra, ra, q8[2 * k]);
                s8[2 * k + 1] += rb;     q8[2 * k + 1] = fmaf(rb, rb, q8[2 * k + 1]);
                ow[k] = (unsigned int)ua | ((unsigned int)ub << 16);
            }
            uint4 o; o.x = ow[0]; o.y = ow[1]; o.z = ow[2]; o.w = ow[3];
            ((uint4*)out)[(size_t)n * 16 + c16] = o;
        }
    }
    // block-level stats reduction: col = c16*8+k, stats[c] = sum, stats[128+c] = sumsq
    __shared__ float red[4 * 16 * 16];
    if (g == 0) {
#pragma unroll
        for (int k = 0; k < 8; ++k) {
            red[(wv * 16 + c16) * 16 + k] = s8[k];
            red[(wv * 16 + c16) * 16 + 8 + k] = q8[k];
        }
    }
    __syncthreads();
    int t = threadIdx.x;
    if (t < 128) {
        int cr = t >> 3, k = t & 7;
        float ss = red[(0 * 16 + cr) * 16 + k] + red[(1 * 16 + cr) * 16 + k] +
                   red[(2 * 16 + cr) * 16 + k] + red[(3 * 16 + cr) * 16 + k];
        float qq = red[(0 * 16 + cr) * 16 + 8 + k] + red[(1 * 16 + cr) * 16 + 8 + k] +
                   red[(2 * 16 + cr) * 16 + 8 + k] + red[(3 * 16 + cr) * 16 + 8 + k];
        atomicAdd(&stats[t], ss);
        atomicAdd(&stats[128 + t], qq);
    }
}

// ---------------- classifier: per-block coef from stats + fused GraphNorm+ELU ----------------
__global__ __launch_bounds__(256) void k_cls(const ushort* __restrict__ X,
                                             const float* __restrict__ stats,
                                             const float* __restrict__ gw,
                                             const float* __restrict__ gb,
                                             const float* __restrict__ gms,
                                             const float* __restrict__ Wc,
                                             const float* __restrict__ bc,
                                             float* __restrict__ out, int Nn) {
    __shared__ __align__(16) float ls[16 * 132];
    __shared__ __align__(16) float wT[13 * 132];
    __shared__ __align__(16) float ABs[256];
    __shared__ float bS[13];
    int t = threadIdx.x;
    int n0 = blockIdx.x * 16;
    if (t < 128) {
        float inv = 1.f / (float)Nn;
        float mean = stats[t] * inv;
        float cm = mean * gms[t];
        float var = stats[128 + t] * inv - 2.f * cm * mean + cm * cm;
        float A = gw[t] * rsqrtf(var + GEPS);
        ABs[t] = A;
        ABs[128 + t] = gb[t] - A * cm;
    }
    for (int i = t; i < 128 * 13; i += 256) {
        int k = i / 13, j = i - k * 13;
        wT[j * 132 + k] = Wc[i];
    }
    if (t < 13) bS[t] = bc[t];
    __syncthreads();
    const unsigned int* xu = (const unsigned int*)X;
    for (int idx = t; idx < 16 * 64; idx += 256) {
        int r = idx >> 6, ku = idx & 63;
        int row = n0 + r;
        float vx = 0.f, vy = 0.f;
        if (row < Nn) {
            float2 v = unpack_bf2(xu[(size_t)row * 64 + ku]);
            int k = 2 * ku;
            vx = elu_fast(fmaf(ABs[k], v.x, ABs[128 + k]));
            vy = elu_fast(fmaf(ABs[k + 1], v.y, ABs[128 + k + 1]));
        }
        ls[r * 132 + 2 * ku] = vx;
        ls[r * 132 + 2 * ku + 1] = vy;
    }
    __syncthreads();
    if (t < 208) {
        int r = t / 13, j = t - r * 13;
        int row = n0 + r;
        if (row < Nn) {
            float acc = bS[j];
            const float* lr = &ls[r * 132];
            const float* wr = &wT[j * 132];
#pragma unroll 8
            for (int k = 0; k < 128; k += 4) {
                float4 a = *(const float4*)&lr[k];
                float4 b = *(const float4*)&wr[k];
                acc = fmaf(a.x, b.x, fmaf(a.y, b.y, fmaf(a.z, b.z, fmaf(a.w, b.w, acc))));
            }
            out[(size_t)row * 13 + j] = acc;
        }
    }
}

extern "C" void kernel_launch(void* const* d_in, const int* in_sizes, int n_in, void* d_out,
                              int out_size, void* d_ws, size_t ws_size, hipStream_t stream) {
    const float* x = (const float*)d_in[0];
    const int* edge_index = (const int*)d_in[1];
    const float* edge_attr = (const float*)d_in[2];
    const float* W1 = (const float*)d_in[3];
    const float* We1 = (const float*)d_in[4];
    const float* as1 = (const float*)d_in[5];
    const float* ad1 = (const float*)d_in[6];
    const float* ae1 = (const float*)d_in[7];
    const float* b1 = (const float*)d_in[8];
    const float* gn1_w = (const float*)d_in[9];
    const float* gn1_b = (const float*)d_in[10];
    const float* gn1_ms = (const float*)d_in[11];
    const float* W2 = (const float*)d_in[12];
    const float* We2 = (const float*)d_in[13];
    const float* as2 = (const float*)d_in[14];
    const float* ad2 = (const float*)d_in[15];
    const float* ae2 = (const float*)d_in[16];
    const float* b2 = (const float*)d_in[17];
    const float* gn2_w = (const float*)d_in[18];
    const float* gn2_b = (const float*)d_in[19];
    const float* gn2_ms = (const float*)d_in[20];
    const float* Wc = (const float*)d_in[21];
    const float* bc = (const float*)d_in[22];

    const int N = in_sizes[0] / 3;
    const int E = in_sizes[1] / 2;
    const int* srcv = edge_index;
    const int* dstv = edge_index + E;

    // ---- workspace carve (256B-aligned, byte-based) ----
    char* w = (char*)d_ws;
    auto carveB = [&](size_t bytes) -> void* {
        void* p = (void*)w;
        w += ((bytes + 255) / 256) * 256;
        return p;
    };
    // zeroed region first:
    int* deg = (int*)carveB((size_t)N * 4);
    float* ea_sum = (float*)carveB(8);
    float* statsA = (float*)carveB(512 * 4);
    float* statsB = (float*)carveB(256 * 4);
    char* zero_end = w;
    // not zeroed:
    int* row_ptr = (int*)carveB((size_t)(N + 1) * 4);
    int* bsum = (int*)carveB(1024 * 4);
    float4* edg = (float4*)carveB((size_t)E * 16);
    float* C1 = (float*)carveB(8 * 4);
    float* lE1 = (float*)carveB(4 * 4);
    float* C2 = (float*)carveB(4 * 4);
    float* lE2 = (float*)carveB(2 * 4);
    uint4* Bfrag = (uint4*)carveB(4096 * 16);
    float* al_s1 = (float*)carveB((size_t)N * 4 * 4);
    float* al_d1 = (float*)carveB((size_t)N * 4 * 4);
    float* al_s2 = (float*)carveB((size_t)N * 2 * 4);
    float* al_d2 = (float*)carveB((size_t)N * 2 * 4);
    ushort* h1b = (ushort*)carveB((size_t)N * 256 * 2);   // bf16 h1; later aliased by out2b
    ushort* h2b = (ushort*)carveB((size_t)N * 128 * 2);   // bf16 h2
    ushort* out1b = (ushort*)carveB((size_t)N * 256 * 2); // bf16 layer-1 output
    ushort* out2b = h1b;                                  // bf16 layer-2 output (h1b dead)

    hipMemsetAsync(deg, 0, (size_t)(zero_end - (char*)deg), stream);

    const int nb1 = (N + 1023) / 1024;
    const int ebl = (E + 255) / 256;
    const int NB1 = (N + 1) / 2;

    k_pre<<<NB1 + 17 + 256, 256, 0, stream>>>(x, W1, as1, ad1, edge_attr, dstv, W2, We1, ae1,
                                              We2, ae2, h1b, al_s1, al_d1, ea_sum, deg, Bfrag,
                                              C1, C2, N, E, NB1);
    k_scan1<<<nb1, 1024, 0, stream>>>(deg, row_ptr, bsum, N);
    k_scan23<<<nb1, 1024, 0, stream>>>(row_ptr, bsum, ea_sum, C1, C2, lE1, lE2, N, E);
    k_scat<<<ebl, 256, 0, stream>>>(dstv, srcv, edge_attr, row_ptr, deg, edg, E);
    k_agg1<<<2048, 256, 0, stream>>>(h1b, row_ptr, edg, al_s1, al_d1, C1, lE1, b1, out1b,
                                     statsA, N);
    k_gemm2_mfma<<<(N + 63) / 64, 256, 0, stream>>>(out1b, statsA, gn1_w, gn1_b, gn1_ms, Bfrag,
                                                    as2, ad2, h2b, al_s2, al_d2, N);
    k_agg2<<<2048, 256, 0, stream>>>(h2b, row_ptr, edg, al_s2, al_d2, C2, lE2, b2, out2b,
                                     statsB, N);
    k_cls<<<(N + 15) / 16, 256, 0, stream>>>(out2b, statsB, gn2_w, gn2_b, gn2_ms, Wc, bc,
                                             (float*)d_out, N);
}

// Round 2
// 320.947 us; speedup vs baseline: 1.1795x; 1.1795x over previous
//
#include <hip/hip_runtime.h>
#include <math.h>

#define NEG_SLOPE 0.2f
#define GEPS 1e-5f

typedef __attribute__((ext_vector_type(8))) short short8;
typedef __attribute__((ext_vector_type(4))) float floatx4;

__device__ __forceinline__ float wave_reduce_sum(float v) {
#pragma unroll
    for (int o = 32; o > 0; o >>= 1) v += __shfl_down(v, o);
    return v;
}

__device__ __forceinline__ ushort f2bf(float f) {
    union { float f; unsigned int i; } c;
    c.f = f;
    unsigned int b = c.i;
    b += 0x7fffu + ((b >> 16) & 1u);
    return (ushort)(b >> 16);
}

__device__ __forceinline__ float bf2f(ushort u) {
    union { unsigned int i; float f; } c;
    c.i = (unsigned int)u << 16;
    return c.f;
}

__device__ __forceinline__ float2 unpack_bf2(unsigned int u) {
    union { unsigned int i; float f; } a, b;
    a.i = u << 16;            // low ushort -> even col
    b.i = u & 0xffff0000u;    // high ushort -> odd col
    return make_float2(a.f, b.f);
}

__device__ __forceinline__ unsigned int pack_bf2(float lo, float hi) {
    return (unsigned int)f2bf(lo) | ((unsigned int)f2bf(hi) << 16);
}

__device__ __forceinline__ float lrelu(float v) {
    return (v > 0.f) ? v : v * NEG_SLOPE;
}

__device__ __forceinline__ float elu_fast(float v) {
    return (v > 0.f) ? v : (__expf(v) - 1.f);
}

// ---------------- merged prologue: layer-1 transform + W2 frag + attn consts + ea/deg ----
// blocks [0, NB1)            : layer-1 transform, 2 nodes per block
// blocks [NB1, NB1+16)       : W2 -> bf16 MFMA B-fragment layout
// block  NB1+16              : C1/C2 attention constants
// blocks [NB1+17, NB1+17+256): edge_attr column sums + degree histogram
__global__ __launch_bounds__(256) void k_pre(
    const float* __restrict__ x, const float* __restrict__ W1,
    const float* __restrict__ as1, const float* __restrict__ ad1,
    const float* __restrict__ ea, const int* __restrict__ dst,
    const float* __restrict__ W2, const float* __restrict__ We1,
    const float* __restrict__ ae1, const float* __restrict__ We2,
    const float* __restrict__ ae2,
    ushort* __restrict__ h1, float* __restrict__ al_s, float* __restrict__ al_d,
    float* __restrict__ ea_sum, int* __restrict__ deg, uint4* __restrict__ Bfrag,
    float* __restrict__ C1, float* __restrict__ C2, int N, int E, int NB1) {
    int b = blockIdx.x;
    if (b < NB1) {
        int u = threadIdx.x >> 7;
        int n = b * 2 + u;
        if (n >= N) return;
        int t = threadIdx.x & 127, lane = threadIdx.x & 63;
        int c0 = 2 * t;
        float x0 = x[3 * n], x1 = x[3 * n + 1], x2 = x[3 * n + 2];
        float h0 = fmaf(x0, W1[c0], fmaf(x1, W1[256 + c0], x2 * W1[512 + c0]));
        float h1v = fmaf(x0, W1[c0 + 1], fmaf(x1, W1[257 + c0], x2 * W1[513 + c0]));
        ((unsigned int*)h1)[(size_t)n * 128 + t] = pack_bf2(h0, h1v);
        float ps = h0 * as1[c0] + h1v * as1[c0 + 1];
        float pd = h0 * ad1[c0] + h1v * ad1[c0 + 1];
#pragma unroll
        for (int o = 16; o > 0; o >>= 1) {
            ps += __shfl_xor(ps, o);
            pd += __shfl_xor(pd, o);
        }
        if ((lane & 31) == 0) {
            int h = c0 >> 6;
            al_s[n * 4 + h] = ps;
            al_d[n * 4 + h] = pd;
        }
        return;
    }
    b -= NB1;
    if (b < 16) {
        int t = b * 256 + threadIdx.x;  // 4096 threads
        int c = t >> 9, kk = (t >> 6) & 7, L = t & 63;
        int q = L >> 4, n = c * 16 + (L & 15);
        int k0 = kk * 32 + q * 8;
        unsigned int u0 = pack_bf2(W2[(k0 + 0) * 128 + n], W2[(k0 + 1) * 128 + n]);
        unsigned int u1 = pack_bf2(W2[(k0 + 2) * 128 + n], W2[(k0 + 3) * 128 + n]);
        unsigned int u2 = pack_bf2(W2[(k0 + 4) * 128 + n], W2[(k0 + 5) * 128 + n]);
        unsigned int u3 = pack_bf2(W2[(k0 + 6) * 128 + n], W2[(k0 + 7) * 128 + n]);
        Bfrag[t] = make_uint4(u0, u1, u2, u3);
        return;
    }
    if (b == 16) {
        int t = threadIdx.x, h = t >> 6, lane = t & 63;
        float p0 = We1[t] * ae1[t];
        float p1 = We1[256 + t] * ae1[t];
        p0 = wave_reduce_sum(p0);
        p1 = wave_reduce_sum(p1);
        if (lane == 0) { C1[h] = p0; C1[4 + h] = p1; }
        if (t < 128) {
            float q0 = We2[t] * ae2[t];
            float q1 = We2[128 + t] * ae2[t];
            q0 = wave_reduce_sum(q0);
            q1 = wave_reduce_sum(q1);
            if (lane == 0) { C2[h] = q0; C2[2 + h] = q1; }
        }
        return;
    }
    b -= 17;
    const float2* ea2 = (const float2*)ea;
    float s0 = 0.f, s1 = 0.f;
    for (int e = b * 256 + threadIdx.x; e < E; e += 256 * 256) {
        float2 v = ea2[e];
        s0 += v.x; s1 += v.y;
        atomicAdd(&deg[dst[e]], 1);
    }
    s0 = wave_reduce_sum(s0);
    s1 = wave_reduce_sum(s1);
    if ((threadIdx.x & 63) == 0) {
        atomicAdd(&ea_sum[0], s0);
        atomicAdd(&ea_sum[1], s1);
    }
}

// ---------------- CSR row_ptr scan (block-local) ----------------
__global__ void k_scan1(const int* __restrict__ deg, int* __restrict__ row_ptr,
                        int* __restrict__ bsum, int N) {
    __shared__ int tmp[1024];
    int tid = threadIdx.x;
    int i = blockIdx.x * 1024 + tid;
    int v = (i < N) ? deg[i] : 0;
    tmp[tid] = v;
    __syncthreads();
#pragma unroll
    for (int off = 1; off < 1024; off <<= 1) {
        int t = (tid >= off) ? tmp[tid - off] : 0;
        __syncthreads();
        tmp[tid] += t;
        __syncthreads();
    }
    if (i < N) row_ptr[i + 1] = tmp[tid];
    if (tid == 1023) bsum[blockIdx.x] = tmp[1023];
}

// block prefix recomputed per block in one wave (nb1 <= 64), then applied.
// also computes the self-loop attention constants lE1/lE2 (needs ea_sum from k_pre).
__global__ void k_scan23(int* __restrict__ row_ptr, const int* __restrict__ bsum,
                         const float* __restrict__ ea_sum, const float* __restrict__ C1,
                         const float* __restrict__ C2, float* __restrict__ lE1,
                         float* __restrict__ lE2, int N, int E) {
    __shared__ int off_s;
    int t = threadIdx.x;
    if (blockIdx.x == 0 && t >= 64 && t < 68) {
        int k = t - 64;
        float m0 = ea_sum[0] / (float)E, m1 = ea_sum[1] / (float)E;
        lE1[k] = m0 * C1[k] + m1 * C1[4 + k];
        if (k < 2) lE2[k] = m0 * C2[k] + m1 * C2[2 + k];
    }
    if (t < 64) {
        int v = (t < blockIdx.x) ? bsum[t] : 0;
#pragma unroll
        for (int o = 32; o > 0; o >>= 1) v += __shfl_xor(v, o);
        if (t == 0) off_s = v;
    }
    __syncthreads();
    int off = off_s;
    int i = blockIdx.x * 1024 + t;
    if (i == 0) row_ptr[0] = 0;
    if (i < N) row_ptr[i + 1] += off;
}

// ---------------- CSR scatter fused with layer-1 edge weights ----------------
// slot via atomicSub on deg (deg is dead after the scan); writes:
//   wmp[slot] = {src, bf16 w0..w3}   (agg1 metadata)
//   ed2[slot] = {src, dst, ea.x, ea.y} (fill2 input)
__global__ void k_scatfill(const int* __restrict__ dst, const int* __restrict__ src,
                           const float* __restrict__ ea, const int* __restrict__ row_ptr,
                           int* __restrict__ deg, const float* __restrict__ al_s1,
                           const float* __restrict__ al_d1, const float* __restrict__ C1,
                           float4* __restrict__ ed2, uint4* __restrict__ wmp, int E) {
    int e = blockIdx.x * 256 + threadIdx.x;
    if (e >= E) return;
    int d = dst[e];
    int r = atomicSub(&deg[d], 1);
    int slot = row_ptr[d] + r - 1;
    int s = src[e];
    float2 v = ((const float2*)ea)[e];
    float4 as = *(const float4*)(al_s1 + 4 * (size_t)s);
    float4 ad = *(const float4*)(al_d1 + 4 * (size_t)d);
    float w0 = __expf(lrelu(as.x + ad.x + v.x * C1[0] + v.y * C1[4]));
    float w1 = __expf(lrelu(as.y + ad.y + v.x * C1[1] + v.y * C1[5]));
    float w2 = __expf(lrelu(as.z + ad.z + v.x * C1[2] + v.y * C1[6]));
    float w3 = __expf(lrelu(as.w + ad.w + v.x * C1[3] + v.y * C1[7]));
    ed2[slot] = make_float4(__int_as_float(s), __int_as_float(d), v.x, v.y);
    wmp[slot] = make_uint4((unsigned int)s, pack_bf2(w0, w1), pack_bf2(w2, w3), 0u);
}

// ---------------- layer-2 edge-weight fill (CSR order) ----------------
__global__ void k_fill2(const float4* __restrict__ ed2, const float* __restrict__ al_s2,
                        const float* __restrict__ al_d2, const float* __restrict__ C2,
                        float4* __restrict__ wm2, int E) {
    int e = blockIdx.x * 256 + threadIdx.x;
    if (e >= E) return;
    float4 m = ed2[e];
    int s = __float_as_int(m.x), d = __float_as_int(m.y);
    float2 as = *(const float2*)(al_s2 + 2 * (size_t)s);
    float2 ad = *(const float2*)(al_d2 + 2 * (size_t)d);
    float wA = __expf(lrelu(as.x + ad.x + m.z * C2[0] + m.w * C2[2]));
    float wB = __expf(lrelu(as.y + ad.y + m.z * C2[1] + m.w * C2[3]));
    wm2[e] = make_float4(m.x, wA, wB, 0.f);
}

// ---------------- layer-1 aggregation: one wave/node, 4-stage gather pipeline ----------
// 2 edge-groups of 32 lanes; metas 4 ahead, gathers 3 ahead -> 6 gathers in flight/wave.
__global__ __launch_bounds__(256) void k_agg1(const ushort* __restrict__ h1,
                                              const int* __restrict__ row_ptr,
                                              const uint4* __restrict__ wmp,
                                              const float* __restrict__ al_s,
                                              const float* __restrict__ al_d,
                                              const float* __restrict__ lE,
                                              const float* __restrict__ bias,
                                              ushort* __restrict__ out, int N) {
    int n = blockIdx.x * 4 + (threadIdx.x >> 6);
    if (n >= N) return;
    int lane = threadIdx.x & 63;
    int g = lane >> 5, c32 = lane & 31;
    int h = c32 >> 3;
    const uint4* h1u4 = (const uint4*)h1;
    float4 as = *(const float4*)(al_s + 4 * (size_t)n);
    float4 ad = *(const float4*)(al_d + 4 * (size_t)n);
    float4 le = *(const float4*)lE;
    float ws0 = __expf(lrelu(as.x + ad.x + le.x));
    float ws1 = __expf(lrelu(as.y + ad.y + le.y));
    float ws2 = __expf(lrelu(as.z + ad.z + le.z));
    float ws3 = __expf(lrelu(as.w + ad.w + le.w));
    float wsh = (h == 0) ? ws0 : (h == 1) ? ws1 : (h == 2) ? ws2 : ws3;
    uint4 hs = h1u4[(size_t)n * 32 + c32];
    float wself = (g == 0) ? wsh : 0.f;
    float dsum = wself;
    float acc[8];
    {
        float2 t0 = unpack_bf2(hs.x), t1 = unpack_bf2(hs.y);
        float2 t2 = unpack_bf2(hs.z), t3 = unpack_bf2(hs.w);
        acc[0] = wself * t0.x; acc[1] = wself * t0.y;
        acc[2] = wself * t1.x; acc[3] = wself * t1.y;
        acc[4] = wself * t2.x; acc[5] = wself * t2.y;
        acc[6] = wself * t3.x; acc[7] = wself * t3.y;
    }
    int i0 = row_ptr[n];
    int cnt = row_ptr[n + 1] - i0;
    if (cnt > 0) {
        int last = cnt - 1;
        int nit = (cnt + 1) >> 1;
        int j0 = g;     float mkA = 1.f; if (j0 > last) { j0 = last; mkA = 0.f; }
        int j1 = 2 + g; float mkB = 1.f; if (j1 > last) { j1 = last; mkB = 0.f; }
        int j2 = 4 + g; float mkC = 1.f; if (j2 > last) { j2 = last; mkC = 0.f; }
        int j3 = 6 + g; float mkD = 1.f; if (j3 > last) { j3 = last; mkD = 0.f; }
        uint4 meA = wmp[i0 + j0];
        uint4 meB = wmp[i0 + j1];
        uint4 meC = wmp[i0 + j2];
        uint4 meD = wmp[i0 + j3];
        uint4 gvA = h1u4[(size_t)meA.x * 32 + c32];
        uint4 gvB = h1u4[(size_t)meB.x * 32 + c32];
        uint4 gvC = h1u4[(size_t)meC.x * 32 + c32];
        for (int it = 0; it < nit - 1; ++it) {
            uint4 gvD = h1u4[(size_t)meD.x * 32 + c32];
            int jn = 2 * (it + 4) + g;
            float mn = 1.f;
            if (jn > last) { jn = last; mn = 0.f; }
            uint4 meE = wmp[i0 + jn];
            float2 w01 = unpack_bf2(meA.y);
            float2 w23 = unpack_bf2(meA.z);
            float2 wp = (h < 2) ? w01 : w23;
            float wg = ((h & 1) ? wp.y : wp.x) * mkA;
            dsum += wg;
            float2 u;
            u = unpack_bf2(gvA.x); acc[0] = fmaf(wg, u.x, acc[0]); acc[1] = fmaf(wg, u.y, acc[1]);
            u = unpack_bf2(gvA.y); acc[2] = fmaf(wg, u.x, acc[2]); acc[3] = fmaf(wg, u.y, acc[3]);
            u = unpack_bf2(gvA.z); acc[4] = fmaf(wg, u.x, acc[4]); acc[5] = fmaf(wg, u.y, acc[5]);
            u = unpack_bf2(gvA.w); acc[6] = fmaf(wg, u.x, acc[6]); acc[7] = fmaf(wg, u.y, acc[7]);
            meA = meB; meB = meC; meC = meD; meD = meE;
            gvA = gvB; gvB = gvC; gvC = gvD;
            mkA = mkB; mkB = mkC; mkC = mkD; mkD = mn;
        }
        float2 w01 = unpack_bf2(meA.y);
        float2 w23 = unpack_bf2(meA.z);
        float2 wp = (h < 2) ? w01 : w23;
        float wg = ((h & 1) ? wp.y : wp.x) * mkA;
        dsum += wg;
        float2 u;
        u = unpack_bf2(gvA.x); acc[0] = fmaf(wg, u.x, acc[0]); acc[1] = fmaf(wg, u.y, acc[1]);
        u = unpack_bf2(gvA.y); acc[2] = fmaf(wg, u.x, acc[2]); acc[3] = fmaf(wg, u.y, acc[3]);
        u = unpack_bf2(gvA.z); acc[4] = fmaf(wg, u.x, acc[4]); acc[5] = fmaf(wg, u.y, acc[5]);
        u = unpack_bf2(gvA.w); acc[6] = fmaf(wg, u.x, acc[6]); acc[7] = fmaf(wg, u.y, acc[7]);
    }
#pragma unroll
    for (int k = 0; k < 8; ++k) acc[k] += __shfl_xor(acc[k], 32);
    dsum += __shfl_xor(dsum, 32);
    if (g == 0) {
        float inv = 1.f / dsum;
        const float* bp = bias + c32 * 8;
        float4 b0 = *(const float4*)bp;
        float4 b1 = *(const float4*)(bp + 4);
        uint4 o;
        o.x = pack_bf2(fmaf(acc[0], inv, b0.x), fmaf(acc[1], inv, b0.y));
        o.y = pack_bf2(fmaf(acc[2], inv, b0.z), fmaf(acc[3], inv, b0.w));
        o.z = pack_bf2(fmaf(acc[4], inv, b1.x), fmaf(acc[5], inv, b1.y));
        o.w = pack_bf2(fmaf(acc[6], inv, b1.z), fmaf(acc[7], inv, b1.w));
        ((uint4*)out)[(size_t)n * 32 + c32] = o;
    }
}

// ---------------- layer-2 aggregation: one wave/node, 4 groups, 4-stage pipeline --------
__global__ __launch_bounds__(256) void k_agg2(const ushort* __restrict__ h2,
                                              const int* __restrict__ row_ptr,
                                              const float4* __restrict__ wm,
                                              const float* __restrict__ al_s,
                                              const float* __restrict__ al_d,
                                              const float* __restrict__ lE,
                                              const float* __restrict__ bias,
                                              ushort* __restrict__ out, int N) {
    int n = blockIdx.x * 4 + (threadIdx.x >> 6);
    if (n >= N) return;
    int lane = threadIdx.x & 63;
    int g = lane >> 4, c16 = lane & 15;
    bool hi = c16 >= 8;
    const uint4* h2u4 = (const uint4*)h2;
    float2 ad = *(const float2*)(al_d + 2 * (size_t)n);
    float2 as = *(const float2*)(al_s + 2 * (size_t)n);
    float wsA = __expf(lrelu(as.x + ad.x + lE[0]));
    float wsB = __expf(lrelu(as.y + ad.y + lE[1]));
    uint4 hs = h2u4[(size_t)n * 16 + c16];
    float wself = (g == 0) ? (hi ? wsB : wsA) : 0.f;
    float dsum = wself;
    float acc[8];
    {
        float2 t0 = unpack_bf2(hs.x), t1 = unpack_bf2(hs.y);
        float2 t2 = unpack_bf2(hs.z), t3 = unpack_bf2(hs.w);
        acc[0] = wself * t0.x; acc[1] = wself * t0.y;
        acc[2] = wself * t1.x; acc[3] = wself * t1.y;
        acc[4] = wself * t2.x; acc[5] = wself * t2.y;
        acc[6] = wself * t3.x; acc[7] = wself * t3.y;
    }
    int i0 = row_ptr[n];
    int cnt = row_ptr[n + 1] - i0;
    if (cnt > 0) {
        int last = cnt - 1;
        int nit = (cnt + 3) >> 2;
        int j0 = g;      float mkA = 1.f; if (j0 > last) { j0 = last; mkA = 0.f; }
        int j1 = 4 + g;  float mkB = 1.f; if (j1 > last) { j1 = last; mkB = 0.f; }
        int j2 = 8 + g;  float mkC = 1.f; if (j2 > last) { j2 = last; mkC = 0.f; }
        int j3 = 12 + g; float mkD = 1.f; if (j3 > last) { j3 = last; mkD = 0.f; }
        float4 meA = wm[i0 + j0];
        float4 meB = wm[i0 + j1];
        float4 meC = wm[i0 + j2];
        float4 meD = wm[i0 + j3];
        uint4 gvA = h2u4[(size_t)__float_as_int(meA.x) * 16 + c16];
        uint4 gvB = h2u4[(size_t)__float_as_int(meB.x) * 16 + c16];
        uint4 gvC = h2u4[(size_t)__float_as_int(meC.x) * 16 + c16];
        for (int it = 0; it < nit - 1; ++it) {
            uint4 gvD = h2u4[(size_t)__float_as_int(meD.x) * 16 + c16];
            int jn = 4 * (it + 4) + g;
            float mn = 1.f;
            if (jn > last) { jn = last; mn = 0.f; }
            float4 meE = wm[i0 + jn];
            float wg = (hi ? meA.z : meA.y) * mkA;
            dsum += wg;
            float2 u;
            u = unpack_bf2(gvA.x); acc[0] = fmaf(wg, u.x, acc[0]); acc[1] = fmaf(wg, u.y, acc[1]);
            u = unpack_bf2(gvA.y); acc[2] = fmaf(wg, u.x, acc[2]); acc[3] = fmaf(wg, u.y, acc[3]);
            u = unpack_bf2(gvA.z); acc[4] = fmaf(wg, u.x, acc[4]); acc[5] = fmaf(wg, u.y, acc[5]);
            u = unpack_bf2(gvA.w); acc[6] = fmaf(wg, u.x, acc[6]); acc[7] = fmaf(wg, u.y, acc[7]);
            meA = meB; meB = meC; meC = meD; meD = meE;
            gvA = gvB; gvB = gvC; gvC = gvD;
            mkA = mkB; mkB = mkC; mkC = mkD; mkD = mn;
        }
        float wg = (hi ? meA.z : meA.y) * mkA;
        dsum += wg;
        float2 u;
        u = unpack_bf2(gvA.x); acc[0] = fmaf(wg, u.x, acc[0]); acc[1] = fmaf(wg, u.y, acc[1]);
        u = unpack_bf2(gvA.y); acc[2] = fmaf(wg, u.x, acc[2]); acc[3] = fmaf(wg, u.y, acc[3]);
        u = unpack_bf2(gvA.z); acc[4] = fmaf(wg, u.x, acc[4]); acc[5] = fmaf(wg, u.y, acc[5]);
        u = unpack_bf2(gvA.w); acc[6] = fmaf(wg, u.x, acc[6]); acc[7] = fmaf(wg, u.y, acc[7]);
    }
#pragma unroll
    for (int k = 0; k < 8; ++k) {
        acc[k] += __shfl_xor(acc[k], 16);
        acc[k] += __shfl_xor(acc[k], 32);
    }
    dsum += __shfl_xor(dsum, 16);
    dsum += __shfl_xor(dsum, 32);
    if (g == 0) {
        float inv = 1.f / dsum;
        const float* bp = bias + c16 * 8;
        float4 b0 = *(const float4*)bp;
        float4 b1 = *(const float4*)(bp + 4);
        uint4 o;
        o.x = pack_bf2(fmaf(acc[0], inv, b0.x), fmaf(acc[1], inv, b0.y));
        o.y = pack_bf2(fmaf(acc[2], inv, b0.z), fmaf(acc[3], inv, b0.w));
        o.z = pack_bf2(fmaf(acc[4], inv, b1.x), fmaf(acc[5], inv, b1.y));
        o.w = pack_bf2(fmaf(acc[6], inv, b1.z), fmaf(acc[7], inv, b1.w));
        ((uint4*)out)[(size_t)n * 16 + c16] = o;
    }
}

// ---------------- GraphNorm column stats: uint4 streaming + LDS tree + few atomics ----------
template <int C4>
__global__ __launch_bounds__(256) void k_stats_bf(const ushort* __restrict__ x,
                                                  float* __restrict__ stats, int rows) {
    const int C = C4 * 8;
    const int RG = 256 / C4;
    int t = threadIdx.x;
    int c = t & (C4 - 1);
    int rg = t / C4;
    int rpb = (rows + gridDim.x - 1) / gridDim.x;
    int r0 = blockIdx.x * rpb;
    int r1 = r0 + rpb;
    if (r1 > rows) r1 = rows;
    const uint4* xu = (const uint4*)x;
    float s[8] = {0.f, 0.f, 0.f, 0.f, 0.f, 0.f, 0.f, 0.f};
    float q[8] = {0.f, 0.f, 0.f, 0.f, 0.f, 0.f, 0.f, 0.f};
    for (int r = r0 + rg; r < r1; r += RG) {
        uint4 v = xu[(size_t)r * C4 + c];
        float2 a0 = unpack_bf2(v.x), a1 = unpack_bf2(v.y);
        float2 a2 = unpack_bf2(v.z), a3 = unpack_bf2(v.w);
        s[0] += a0.x; q[0] = fmaf(a0.x, a0.x, q[0]);
        s[1] += a0.y; q[1] = fmaf(a0.y, a0.y, q[1]);
        s[2] += a1.x; q[2] = fmaf(a1.x, a1.x, q[2]);
        s[3] += a1.y; q[3] = fmaf(a1.y, a1.y, q[3]);
        s[4] += a2.x; q[4] = fmaf(a2.x, a2.x, q[4]);
        s[5] += a2.y; q[5] = fmaf(a2.y, a2.y, q[5]);
        s[6] += a3.x; q[6] = fmaf(a3.x, a3.x, q[6]);
        s[7] += a3.y; q[7] = fmaf(a3.y, a3.y, q[7]);
    }
    __shared__ float ls[256 * 16];
#pragma unroll
    for (int k = 0; k < 8; ++k) {
        ls[t * 16 + k] = s[k];
        ls[t * 16 + 8 + k] = q[k];
    }
    __syncthreads();
    if (t < C) {
        int cc = t >> 3, k = t & 7;
        float ssum = 0.f, qsum = 0.f;
#pragma unroll
        for (int g = 0; g < RG; ++g) {
            ssum += ls[(g * C4 + cc) * 16 + k];
            qsum += ls[(g * C4 + cc) * 16 + 8 + k];
        }
        atomicAdd(&stats[t], ssum);
        atomicAdd(&stats[C + t], qsum);
    }
}

// ---------------- MFMA GEMM2 + per-block coef from stats + fused layer-2 attn dots ----------
__global__ __launch_bounds__(256) void k_gemm2_mfma(const ushort* __restrict__ X,
                                                    const float* __restrict__ stats,
                                                    const float* __restrict__ gw,
                                                    const float* __restrict__ gb,
                                                    const float* __restrict__ gms,
                                                    const uint4* __restrict__ Bfrag,
                                                    const float* __restrict__ as2,
                                                    const float* __restrict__ ad2,
                                                    ushort* __restrict__ H2,
                                                    float* __restrict__ al_s,
                                                    float* __restrict__ al_d, int Nn) {
    __shared__ __align__(16) float ABs[512];
    {
        int t = threadIdx.x;
        float inv = 1.f / (float)Nn;
        float mean = stats[t] * inv;
        float cm = mean * gms[t];
        float var = stats[256 + t] * inv - 2.f * cm * mean + cm * cm;
        float A = gw[t] * rsqrtf(var + GEPS);
        ABs[t] = A;
        ABs[256 + t] = gb[t] - A * cm;
    }
    __syncthreads();
    int wave = threadIdx.x >> 6, lane = threadIdx.x & 63;
    int q = lane >> 4, m = lane & 15;
    int rowbase = blockIdx.x * 64 + wave * 16;
    int row = rowbase + m;
    bool valid = row < Nn;
    const uint4* xr4 = (const uint4*)((const unsigned int*)X + (size_t)row * 128);
    uint4 xa[8];
#pragma unroll
    for (int kk = 0; kk < 8; ++kk) {
        int k0 = kk * 32 + q * 8;
        xa[kk] = valid ? xr4[k0 >> 3] : make_uint4(0, 0, 0, 0);
    }
    union { short8 s; unsigned int u[4]; } af[8];
#pragma unroll
    for (int kk = 0; kk < 8; ++kk) {
        int k0 = kk * 32 + q * 8;
        float2 x01 = unpack_bf2(xa[kk].x);
        float2 x23 = unpack_bf2(xa[kk].y);
        float2 x45 = unpack_bf2(xa[kk].z);
        float2 x67 = unpack_bf2(xa[kk].w);
        float4 a0 = *(const float4*)(ABs + k0);
        float4 a1 = *(const float4*)(ABs + k0 + 4);
        float4 b0 = *(const float4*)(ABs + 256 + k0);
        float4 b1 = *(const float4*)(ABs + 256 + k0 + 4);
        float v0 = elu_fast(fmaf(a0.x, x01.x, b0.x));
        float v1 = elu_fast(fmaf(a0.y, x01.y, b0.y));
        float v2 = elu_fast(fmaf(a0.z, x23.x, b0.z));
        float v3 = elu_fast(fmaf(a0.w, x23.y, b0.w));
        float v4 = elu_fast(fmaf(a1.x, x45.x, b1.x));
        float v5 = elu_fast(fmaf(a1.y, x45.y, b1.y));
        float v6 = elu_fast(fmaf(a1.z, x67.x, b1.z));
        float v7 = elu_fast(fmaf(a1.w, x67.y, b1.w));
        af[kk].u[0] = pack_bf2(v0, v1);
        af[kk].u[1] = pack_bf2(v2, v3);
        af[kk].u[2] = pack_bf2(v4, v5);
        af[kk].u[3] = pack_bf2(v6, v7);
    }
    floatx4 acc[8];
#pragma unroll
    for (int c = 0; c < 8; ++c) acc[c] = (floatx4){0.f, 0.f, 0.f, 0.f};
#pragma unroll
    for (int kk = 0; kk < 8; ++kk) {
        const uint4* bpf = Bfrag + kk * 64 + lane;
#pragma unroll
        for (int c = 0; c < 8; ++c) {
            union { short8 s; uint4 u; } bf;
            bf.u = bpf[c * 8 * 64];
            acc[c] = __builtin_amdgcn_mfma_f32_16x16x32_bf16(af[kk].s, bf.s, acc[c], 0, 0, 0);
        }
    }
    float a_s[8], a_d[8];
#pragma unroll
    for (int c = 0; c < 8; ++c) {
        a_s[c] = as2[c * 16 + m];
        a_d[c] = ad2[c * 16 + m];
    }
#pragma unroll
    for (int r = 0; r < 4; ++r) {
        int orow = rowbase + q * 4 + r;
        bool vr = orow < Nn;
        ushort us[8];
        float s0 = 0.f, s1 = 0.f, d0 = 0.f, d1 = 0.f;
#pragma unroll
        for (int c = 0; c < 8; ++c) {
            us[c] = f2bf(acc[c][r]);
            float v = bf2f(us[c]);
            if (c < 4) {
                s0 = fmaf(v, a_s[c], s0);
                d0 = fmaf(v, a_d[c], d0);
            } else {
                s1 = fmaf(v, a_s[c], s1);
                d1 = fmaf(v, a_d[c], d1);
            }
        }
#pragma unroll
        for (int o = 1; o < 16; o <<= 1) {
            s0 += __shfl_xor(s0, o);
            s1 += __shfl_xor(s1, o);
            d0 += __shfl_xor(d0, o);
            d1 += __shfl_xor(d1, o);
        }
        if (vr) {
            ushort* op = H2 + (size_t)orow * 128 + m;
#pragma unroll
            for (int c = 0; c < 8; ++c) op[c * 16] = us[c];
            if (m == 0) {
                *(float2*)(al_s + 2 * (size_t)orow) = make_float2(s0, s1);
                *(float2*)(al_d + 2 * (size_t)orow) = make_float2(d0, d1);
            }
        }
    }
}

// ---------------- classifier: per-block coef from stats + fused GraphNorm+ELU ----------------
__global__ __launch_bounds__(256) void k_cls(const ushort* __restrict__ X,
                                             const float* __restrict__ stats,
                                             const float* __restrict__ gw,
                                             const float* __restrict__ gb,
                                             const float* __restrict__ gms,
                                             const float* __restrict__ Wc,
                                             const float* __restrict__ bc,
                                             float* __restrict__ out, int Nn) {
    __shared__ __align__(16) float ls[16 * 132];
    __shared__ __align__(16) float wT[13 * 132];
    __shared__ __align__(16) float ABs[256];
    __shared__ float bS[13];
    int t = threadIdx.x;
    int n0 = blockIdx.x * 16;
    if (t < 128) {
        float inv = 1.f / (float)Nn;
        float mean = stats[t] * inv;
        float cm = mean * gms[t];
        float var = stats[128 + t] * inv - 2.f * cm * mean + cm * cm;
        float A = gw[t] * rsqrtf(var + GEPS);
        ABs[t] = A;
        ABs[128 + t] = gb[t] - A * cm;
    }
    for (int i = t; i < 128 * 13; i += 256) {
        int k = i / 13, j = i - k * 13;
        wT[j * 132 + k] = Wc[i];
    }
    if (t < 13) bS[t] = bc[t];
    __syncthreads();
    const unsigned int* xu = (const unsigned int*)X;
    for (int idx = t; idx < 16 * 64; idx += 256) {
        int r = idx >> 6, ku = idx & 63;
        int row = n0 + r;
        float vx = 0.f, vy = 0.f;
        if (row < Nn) {
            float2 v = unpack_bf2(xu[(size_t)row * 64 + ku]);
            int k = 2 * ku;
            vx = elu_fast(fmaf(ABs[k], v.x, ABs[128 + k]));
            vy = elu_fast(fmaf(ABs[k + 1], v.y, ABs[128 + k + 1]));
        }
        ls[r * 132 + 2 * ku] = vx;
        ls[r * 132 + 2 * ku + 1] = vy;
    }
    __syncthreads();
    if (t < 208) {
        int r = t / 13, j = t - r * 13;
        int row = n0 + r;
        if (row < Nn) {
            float acc = bS[j];
            const float* lr = &ls[r * 132];
            const float* wr = &wT[j * 132];
#pragma unroll 8
            for (int k = 0; k < 128; k += 4) {
                float4 a = *(const float4*)&lr[k];
                float4 b = *(const float4*)&wr[k];
                acc = fmaf(a.x, b.x, fmaf(a.y, b.y, fmaf(a.z, b.z, fmaf(a.w, b.w, acc))));
            }
            out[(size_t)row * 13 + j] = acc;
        }
    }
}

extern "C" void kernel_launch(void* const* d_in, const int* in_sizes, int n_in, void* d_out,
                              int out_size, void* d_ws, size_t ws_size, hipStream_t stream) {
    const float* x = (const float*)d_in[0];
    const int* edge_index = (const int*)d_in[1];
    const float* edge_attr = (const float*)d_in[2];
    const float* W1 = (const float*)d_in[3];
    const float* We1 = (const float*)d_in[4];
    const float* as1 = (const float*)d_in[5];
    const float* ad1 = (const float*)d_in[6];
    const float* ae1 = (const float*)d_in[7];
    const float* b1 = (const float*)d_in[8];
    const float* gn1_w = (const float*)d_in[9];
    const float* gn1_b = (const float*)d_in[10];
    const float* gn1_ms = (const float*)d_in[11];
    const float* W2 = (const float*)d_in[12];
    const float* We2 = (const float*)d_in[13];
    const float* as2 = (const float*)d_in[14];
    const float* ad2 = (const float*)d_in[15];
    const float* ae2 = (const float*)d_in[16];
    const float* b2 = (const float*)d_in[17];
    const float* gn2_w = (const float*)d_in[18];
    const float* gn2_b = (const float*)d_in[19];
    const float* gn2_ms = (const float*)d_in[20];
    const float* Wc = (const float*)d_in[21];
    const float* bc = (const float*)d_in[22];

    const int N = in_sizes[0] / 3;
    const int E = in_sizes[1] / 2;
    const int* srcv = edge_index;
    const int* dstv = edge_index + E;

    // ---- workspace carve (256B-aligned, byte-based) ----
    char* w = (char*)d_ws;
    auto carveB = [&](size_t bytes) -> void* {
        void* p = (void*)w;
        w += ((bytes + 255) / 256) * 256;
        return p;
    };
    // zeroed region first:
    int* deg = (int*)carveB((size_t)N * 4);
    float* ea_sum = (float*)carveB(8);
    float* statsA = (float*)carveB(512 * 4);
    float* statsB = (float*)carveB(256 * 4);
    char* zero_end = w;
    // not zeroed:
    int* row_ptr = (int*)carveB((size_t)(N + 1) * 4);
    int* bsum = (int*)carveB(1024 * 4);
    float4* ed2 = (float4*)carveB((size_t)E * 16);
    uint4* wmp = (uint4*)carveB((size_t)E * 16);
    float4* wm2 = (float4*)wmp;  // layer-2 weights reuse (wmp dead after agg1)
    float* C1 = (float*)carveB(8 * 4);
    float* lE1 = (float*)carveB(4 * 4);
    float* C2 = (float*)carveB(4 * 4);
    float* lE2 = (float*)carveB(2 * 4);
    uint4* Bfrag = (uint4*)carveB(4096 * 16);
    float* al_s1 = (float*)carveB((size_t)N * 4 * 4);
    float* al_d1 = (float*)carveB((size_t)N * 4 * 4);
    float* al_s2 = (float*)carveB((size_t)N * 2 * 4);
    float* al_d2 = (float*)carveB((size_t)N * 2 * 4);
    ushort* h1b = (ushort*)carveB((size_t)N * 256 * 2);   // bf16 h1; later aliased by out2b
    ushort* h2b = (ushort*)carveB((size_t)N * 128 * 2);   // bf16 h2
    ushort* out1b = (ushort*)carveB((size_t)N * 256 * 2); // bf16 layer-1 output
    ushort* out2b = h1b;                                  // bf16 layer-2 output (h1b dead)

    hipMemsetAsync(deg, 0, (size_t)(zero_end - (char*)deg), stream);

    const int nb1 = (N + 1023) / 1024;
    const int ebl = (E + 255) / 256;
    const int NB1 = (N + 1) / 2;

    k_pre<<<NB1 + 17 + 256, 256, 0, stream>>>(x, W1, as1, ad1, edge_attr, dstv, W2, We1, ae1,
                                              We2, ae2, h1b, al_s1, al_d1, ea_sum, deg, Bfrag,
                                              C1, C2, N, E, NB1);
    k_scan1<<<nb1, 1024, 0, stream>>>(deg, row_ptr, bsum, N);
    k_scan23<<<nb1, 1024, 0, stream>>>(row_ptr, bsum, ea_sum, C1, C2, lE1, lE2, N, E);
    k_scatfill<<<ebl, 256, 0, stream>>>(dstv, srcv, edge_attr, row_ptr, deg, al_s1, al_d1, C1,
                                        ed2, wmp, E);
    k_agg1<<<(N + 3) / 4, 256, 0, stream>>>(h1b, row_ptr, wmp, al_s1, al_d1, lE1, b1, out1b, N);
    k_stats_bf<32><<<256, 256, 0, stream>>>(out1b, statsA, N);
    k_gemm2_mfma<<<(N + 63) / 64, 256, 0, stream>>>(out1b, statsA, gn1_w, gn1_b, gn1_ms, Bfrag,
                                                    as2, ad2, h2b, al_s2, al_d2, N);
    k_fill2<<<ebl, 256, 0, stream>>>(ed2, al_s2, al_d2, C2, wm2, E);
    k_agg2<<<(N + 3) / 4, 256, 0, stream>>>(h2b, row_ptr, wm2, al_s2, al_d2, lE2, b2, out2b, N);
    k_stats_bf<16><<<256, 256, 0, stream>>>(out2b, statsB, N);
    k_cls<<<(N + 15) / 16, 256, 0, stream>>>(out2b, statsB, gn2_w, gn2_b, gn2_ms, Wc, bc,
                                             (float*)d_out, N);
}

// Round 3
// 306.407 us; speedup vs baseline: 1.2354x; 1.0475x over previous
//
#include <hip/hip_runtime.h>
#include <math.h>

#define NEG_SLOPE 0.2f
#define GEPS 1e-5f
#define TBLK 1024

typedef __attribute__((ext_vector_type(8))) short short8;
typedef __attribute__((ext_vector_type(4))) float floatx4;

__device__ __forceinline__ float wave_reduce_sum(float v) {
#pragma unroll
    for (int o = 32; o > 0; o >>= 1) v += __shfl_down(v, o);
    return v;
}

__device__ __forceinline__ ushort f2bf(float f) {
    union { float f; unsigned int i; } c;
    c.f = f;
    unsigned int b = c.i;
    b += 0x7fffu + ((b >> 16) & 1u);
    return (ushort)(b >> 16);
}

__device__ __forceinline__ float bf2f(ushort u) {
    union { unsigned int i; float f; } c;
    c.i = (unsigned int)u << 16;
    return c.f;
}

__device__ __forceinline__ float2 unpack_bf2(unsigned int u) {
    union { unsigned int i; float f; } a, b;
    a.i = u << 16;            // low ushort -> even col
    b.i = u & 0xffff0000u;    // high ushort -> odd col
    return make_float2(a.f, b.f);
}

__device__ __forceinline__ unsigned int pack_bf2(float lo, float hi) {
    return (unsigned int)f2bf(lo) | ((unsigned int)f2bf(hi) << 16);
}

__device__ __forceinline__ float lrelu(float v) {
    return (v > 0.f) ? v : v * NEG_SLOPE;
}

__device__ __forceinline__ float elu_fast(float v) {
    return (v > 0.f) ? v : (__expf(v) - 1.f);
}

// ---------------- merged prologue ----------------
// blocks [0, TBLK)            : layer-1 transform, grid-stride, reg-resident W1 (8 nodes/blk/iter)
// blocks [TBLK, TBLK+16)      : W2 -> bf16 MFMA B-fragment layout
// block  TBLK+16              : C1/C2 attention constants
// blocks [TBLK+17, TBLK+17+256): edge_attr column sums + degree histogram
__global__ __launch_bounds__(256) void k_pre(
    const float* __restrict__ x, const float* __restrict__ W1,
    const float* __restrict__ as1, const float* __restrict__ ad1,
    const float* __restrict__ ea, const int* __restrict__ dst,
    const float* __restrict__ W2, const float* __restrict__ We1,
    const float* __restrict__ ae1, const float* __restrict__ We2,
    const float* __restrict__ ae2,
    ushort* __restrict__ h1, float* __restrict__ al_s, float* __restrict__ al_d,
    float* __restrict__ ea_sum, int* __restrict__ deg, uint4* __restrict__ Bfrag,
    float* __restrict__ C1, float* __restrict__ C2, int N, int E) {
    int b = blockIdx.x;
    if (b < TBLK) {
        int g32 = threadIdx.x >> 5;   // 8 node-groups per block
        int l = threadIdx.x & 31;     // lane in group
        int c0 = l * 8;               // column base (8 cols per lane)
        int h = l >> 3;               // head (64 cols per head)
        // loop-invariant weights in registers: 24 W1 + 8 as1 + 8 ad1
        float4 wa0 = *(const float4*)(W1 + c0);
        float4 wa1 = *(const float4*)(W1 + c0 + 4);
        float4 wb0 = *(const float4*)(W1 + 256 + c0);
        float4 wb1 = *(const float4*)(W1 + 256 + c0 + 4);
        float4 wc0 = *(const float4*)(W1 + 512 + c0);
        float4 wc1 = *(const float4*)(W1 + 512 + c0 + 4);
        float4 sv0 = *(const float4*)(as1 + c0);
        float4 sv1 = *(const float4*)(as1 + c0 + 4);
        float4 dv0 = *(const float4*)(ad1 + c0);
        float4 dv1 = *(const float4*)(ad1 + c0 + 4);
        for (int n = b * 8 + g32; n < N; n += TBLK * 8) {
            float x0 = x[3 * n], x1 = x[3 * n + 1], x2 = x[3 * n + 2];
            float v0 = fmaf(x0, wa0.x, fmaf(x1, wb0.x, x2 * wc0.x));
            float v1 = fmaf(x0, wa0.y, fmaf(x1, wb0.y, x2 * wc0.y));
            float v2 = fmaf(x0, wa0.z, fmaf(x1, wb0.z, x2 * wc0.z));
            float v3 = fmaf(x0, wa0.w, fmaf(x1, wb0.w, x2 * wc0.w));
            float v4 = fmaf(x0, wa1.x, fmaf(x1, wb1.x, x2 * wc1.x));
            float v5 = fmaf(x0, wa1.y, fmaf(x1, wb1.y, x2 * wc1.y));
            float v6 = fmaf(x0, wa1.z, fmaf(x1, wb1.z, x2 * wc1.z));
            float v7 = fmaf(x0, wa1.w, fmaf(x1, wb1.w, x2 * wc1.w));
            uint4 o;
            o.x = pack_bf2(v0, v1);
            o.y = pack_bf2(v2, v3);
            o.z = pack_bf2(v4, v5);
            o.w = pack_bf2(v6, v7);
            ((uint4*)h1)[(size_t)n * 32 + l] = o;
            float ps = v0 * sv0.x + v1 * sv0.y + v2 * sv0.z + v3 * sv0.w +
                       v4 * sv1.x + v5 * sv1.y + v6 * sv1.z + v7 * sv1.w;
            float pd = v0 * dv0.x + v1 * dv0.y + v2 * dv0.z + v3 * dv0.w +
                       v4 * dv1.x + v5 * dv1.y + v6 * dv1.z + v7 * dv1.w;
            ps += __shfl_xor(ps, 1); ps += __shfl_xor(ps, 2); ps += __shfl_xor(ps, 4);
            pd += __shfl_xor(pd, 1); pd += __shfl_xor(pd, 2); pd += __shfl_xor(pd, 4);
            if ((l & 7) == 0) {
                al_s[n * 4 + h] = ps;
                al_d[n * 4 + h] = pd;
            }
        }
        return;
    }
    b -= TBLK;
    if (b < 16) {
        int t = b * 256 + threadIdx.x;  // 4096 threads
        int c = t >> 9, kk = (t >> 6) & 7, L = t & 63;
        int q = L >> 4, n = c * 16 + (L & 15);
        int k0 = kk * 32 + q * 8;
        unsigned int u0 = pack_bf2(W2[(k0 + 0) * 128 + n], W2[(k0 + 1) * 128 + n]);
        unsigned int u1 = pack_bf2(W2[(k0 + 2) * 128 + n], W2[(k0 + 3) * 128 + n]);
        unsigned int u2 = pack_bf2(W2[(k0 + 4) * 128 + n], W2[(k0 + 5) * 128 + n]);
        unsigned int u3 = pack_bf2(W2[(k0 + 6) * 128 + n], W2[(k0 + 7) * 128 + n]);
        Bfrag[t] = make_uint4(u0, u1, u2, u3);
        return;
    }
    if (b == 16) {
        int t = threadIdx.x, h = t >> 6, lane = t & 63;
        float p0 = We1[t] * ae1[t];
        float p1 = We1[256 + t] * ae1[t];
        p0 = wave_reduce_sum(p0);
        p1 = wave_reduce_sum(p1);
        if (lane == 0) { C1[h] = p0; C1[4 + h] = p1; }
        if (t < 128) {
            float q0 = We2[t] * ae2[t];
            float q1 = We2[128 + t] * ae2[t];
            q0 = wave_reduce_sum(q0);
            q1 = wave_reduce_sum(q1);
            if (lane == 0) { C2[h] = q0; C2[2 + h] = q1; }
        }
        return;
    }
    b -= 17;
    const float2* ea2 = (const float2*)ea;
    float s0 = 0.f, s1 = 0.f;
    for (int e = b * 256 + threadIdx.x; e < E; e += 256 * 256) {
        float2 v = ea2[e];
        s0 += v.x; s1 += v.y;
        atomicAdd(&deg[dst[e]], 1);
    }
    s0 = wave_reduce_sum(s0);
    s1 = wave_reduce_sum(s1);
    if ((threadIdx.x & 63) == 0) {
        atomicAdd(&ea_sum[0], s0);
        atomicAdd(&ea_sum[1], s1);
    }
}

// ---------------- CSR row_ptr scan (block-local) ----------------
__global__ void k_scan1(const int* __restrict__ deg, int* __restrict__ row_ptr,
                        int* __restrict__ bsum, int N) {
    __shared__ int tmp[1024];
    int tid = threadIdx.x;
    int i = blockIdx.x * 1024 + tid;
    int v = (i < N) ? deg[i] : 0;
    tmp[tid] = v;
    __syncthreads();
#pragma unroll
    for (int off = 1; off < 1024; off <<= 1) {
        int t = (tid >= off) ? tmp[tid - off] : 0;
        __syncthreads();
        tmp[tid] += t;
        __syncthreads();
    }
    if (i < N) row_ptr[i + 1] = tmp[tid];
    if (tid == 1023) bsum[blockIdx.x] = tmp[1023];
}

// block prefix recomputed per block in one wave (nb1 <= 64), then applied.
// also computes the self-loop attention constants lE1/lE2 (needs ea_sum from k_pre).
__global__ void k_scan23(int* __restrict__ row_ptr, const int* __restrict__ bsum,
                         const float* __restrict__ ea_sum, const float* __restrict__ C1,
                         const float* __restrict__ C2, float* __restrict__ lE1,
                         float* __restrict__ lE2, int N, int E) {
    __shared__ int off_s;
    int t = threadIdx.x;
    if (blockIdx.x == 0 && t >= 64 && t < 68) {
        int k = t - 64;
        float m0 = ea_sum[0] / (float)E, m1 = ea_sum[1] / (float)E;
        lE1[k] = m0 * C1[k] + m1 * C1[4 + k];
        if (k < 2) lE2[k] = m0 * C2[k] + m1 * C2[2 + k];
    }
    if (t < 64) {
        int v = (t < blockIdx.x) ? bsum[t] : 0;
#pragma unroll
        for (int o = 32; o > 0; o >>= 1) v += __shfl_xor(v, o);
        if (t == 0) off_s = v;
    }
    __syncthreads();
    int off = off_s;
    int i = blockIdx.x * 1024 + t;
    if (i == 0) row_ptr[0] = 0;
    if (i < N) row_ptr[i + 1] += off;
}

// ---------------- CSR scatter fused with layer-1 edge weights ----------------
// slot via atomicSub on deg (deg is dead after the scan); writes:
//   wmp[slot] = {src, bf16 w0..w3}   (agg1 metadata)
//   ed2[slot] = {src, dst, ea.x, ea.y} (fill2 input)
__global__ void k_scatfill(const int* __restrict__ dst, const int* __restrict__ src,
                           const float* __restrict__ ea, const int* __restrict__ row_ptr,
                           int* __restrict__ deg, const float* __restrict__ al_s1,
                           const float* __restrict__ al_d1, const float* __restrict__ C1,
                           float4* __restrict__ ed2, uint4* __restrict__ wmp, int E) {
    int e = blockIdx.x * 256 + threadIdx.x;
    if (e >= E) return;
    int d = dst[e];
    int r = atomicSub(&deg[d], 1);
    int slot = row_ptr[d] + r - 1;
    int s = src[e];
    float2 v = ((const float2*)ea)[e];
    float4 as = *(const float4*)(al_s1 + 4 * (size_t)s);
    float4 ad = *(const float4*)(al_d1 + 4 * (size_t)d);
    float w0 = __expf(lrelu(as.x + ad.x + v.x * C1[0] + v.y * C1[4]));
    float w1 = __expf(lrelu(as.y + ad.y + v.x * C1[1] + v.y * C1[5]));
    float w2 = __expf(lrelu(as.z + ad.z + v.x * C1[2] + v.y * C1[6]));
    float w3 = __expf(lrelu(as.w + ad.w + v.x * C1[3] + v.y * C1[7]));
    ed2[slot] = make_float4(__int_as_float(s), __int_as_float(d), v.x, v.y);
    wmp[slot] = make_uint4((unsigned int)s, pack_bf2(w0, w1), pack_bf2(w2, w3), 0u);
}

// ---------------- layer-2 edge-weight fill (CSR order) ----------------
__global__ void k_fill2(const float4* __restrict__ ed2, const float* __restrict__ al_s2,
                        const float* __restrict__ al_d2, const float* __restrict__ C2,
                        float4* __restrict__ wm2, int E) {
    int e = blockIdx.x * 256 + threadIdx.x;
    if (e >= E) return;
    float4 m = ed2[e];
    int s = __float_as_int(m.x), d = __float_as_int(m.y);
    float2 as = *(const float2*)(al_s2 + 2 * (size_t)s);
    float2 ad = *(const float2*)(al_d2 + 2 * (size_t)d);
    float wA = __expf(lrelu(as.x + ad.x + m.z * C2[0] + m.w * C2[2]));
    float wB = __expf(lrelu(as.y + ad.y + m.z * C2[1] + m.w * C2[3]));
    wm2[e] = make_float4(m.x, wA, wB, 0.f);
}

// ---------------- layer-1 aggregation: one wave/node, 4-stage gather pipeline ----------
__global__ __launch_bounds__(256) void k_agg1(const ushort* __restrict__ h1,
                                              const int* __restrict__ row_ptr,
                                              const uint4* __restrict__ wmp,
                                              const float* __restrict__ al_s,
                                              const float* __restrict__ al_d,
                                              const float* __restrict__ lE,
                                              const float* __restrict__ bias,
                                              ushort* __restrict__ out, int N) {
    int n = blockIdx.x * 4 + (threadIdx.x >> 6);
    if (n >= N) return;
    int lane = threadIdx.x & 63;
    int g = lane >> 5, c32 = lane & 31;
    int h = c32 >> 3;
    const uint4* h1u4 = (const uint4*)h1;
    float4 as = *(const float4*)(al_s + 4 * (size_t)n);
    float4 ad = *(const float4*)(al_d + 4 * (size_t)n);
    float4 le = *(const float4*)lE;
    float ws0 = __expf(lrelu(as.x + ad.x + le.x));
    float ws1 = __expf(lrelu(as.y + ad.y + le.y));
    float ws2 = __expf(lrelu(as.z + ad.z + le.z));
    float ws3 = __expf(lrelu(as.w + ad.w + le.w));
    float wsh = (h == 0) ? ws0 : (h == 1) ? ws1 : (h == 2) ? ws2 : ws3;
    uint4 hs = h1u4[(size_t)n * 32 + c32];
    float wself = (g == 0) ? wsh : 0.f;
    float dsum = wself;
    float acc[8];
    {
        float2 t0 = unpack_bf2(hs.x), t1 = unpack_bf2(hs.y);
        float2 t2 = unpack_bf2(hs.z), t3 = unpack_bf2(hs.w);
        acc[0] = wself * t0.x; acc[1] = wself * t0.y;
        acc[2] = wself * t1.x; acc[3] = wself * t1.y;
        acc[4] = wself * t2.x; acc[5] = wself * t2.y;
        acc[6] = wself * t3.x; acc[7] = wself * t3.y;
    }
    int i0 = row_ptr[n];
    int cnt = row_ptr[n + 1] - i0;
    if (cnt > 0) {
        int last = cnt - 1;
        int nit = (cnt + 1) >> 1;
        int j0 = g;     float mkA = 1.f; if (j0 > last) { j0 = last; mkA = 0.f; }
        int j1 = 2 + g; float mkB = 1.f; if (j1 > last) { j1 = last; mkB = 0.f; }
        int j2 = 4 + g; float mkC = 1.f; if (j2 > last) { j2 = last; mkC = 0.f; }
        int j3 = 6 + g; float mkD = 1.f; if (j3 > last) { j3 = last; mkD = 0.f; }
        uint4 meA = wmp[i0 + j0];
        uint4 meB = wmp[i0 + j1];
        uint4 meC = wmp[i0 + j2];
        uint4 meD = wmp[i0 + j3];
        uint4 gvA = h1u4[(size_t)meA.x * 32 + c32];
        uint4 gvB = h1u4[(size_t)meB.x * 32 + c32];
        uint4 gvC = h1u4[(size_t)meC.x * 32 + c32];
        for (int it = 0; it < nit - 1; ++it) {
            uint4 gvD = h1u4[(size_t)meD.x * 32 + c32];
            int jn = 2 * (it + 4) + g;
            float mn = 1.f;
            if (jn > last) { jn = last; mn = 0.f; }
            uint4 meE = wmp[i0 + jn];
            float2 w01 = unpack_bf2(meA.y);
            float2 w23 = unpack_bf2(meA.z);
            float2 wp = (h < 2) ? w01 : w23;
            float wg = ((h & 1) ? wp.y : wp.x) * mkA;
            dsum += wg;
            float2 u;
            u = unpack_bf2(gvA.x); acc[0] = fmaf(wg, u.x, acc[0]); acc[1] = fmaf(wg, u.y, acc[1]);
            u = unpack_bf2(gvA.y); acc[2] = fmaf(wg, u.x, acc[2]); acc[3] = fmaf(wg, u.y, acc[3]);
            u = unpack_bf2(gvA.z); acc[4] = fmaf(wg, u.x, acc[4]); acc[5] = fmaf(wg, u.y, acc[5]);
            u = unpack_bf2(gvA.w); acc[6] = fmaf(wg, u.x, acc[6]); acc[7] = fmaf(wg, u.y, acc[7]);
            meA = meB; meB = meC; meC = meD; meD = meE;
            gvA = gvB; gvB = gvC; gvC = gvD;
            mkA = mkB; mkB = mkC; mkC = mkD; mkD = mn;
        }
        float2 w01 = unpack_bf2(meA.y);
        float2 w23 = unpack_bf2(meA.z);
        float2 wp = (h < 2) ? w01 : w23;
        float wg = ((h & 1) ? wp.y : wp.x) * mkA;
        dsum += wg;
        float2 u;
        u = unpack_bf2(gvA.x); acc[0] = fmaf(wg, u.x, acc[0]); acc[1] = fmaf(wg, u.y, acc[1]);
        u = unpack_bf2(gvA.y); acc[2] = fmaf(wg, u.x, acc[2]); acc[3] = fmaf(wg, u.y, acc[3]);
        u = unpack_bf2(gvA.z); acc[4] = fmaf(wg, u.x, acc[4]); acc[5] = fmaf(wg, u.y, acc[5]);
        u = unpack_bf2(gvA.w); acc[6] = fmaf(wg, u.x, acc[6]); acc[7] = fmaf(wg, u.y, acc[7]);
    }
#pragma unroll
    for (int k = 0; k < 8; ++k) acc[k] += __shfl_xor(acc[k], 32);
    dsum += __shfl_xor(dsum, 32);
    if (g == 0) {
        float inv = 1.f / dsum;
        const float* bp = bias + c32 * 8;
        float4 b0 = *(const float4*)bp;
        float4 b1 = *(const float4*)(bp + 4);
        uint4 o;
        o.x = pack_bf2(fmaf(acc[0], inv, b0.x), fmaf(acc[1], inv, b0.y));
        o.y = pack_bf2(fmaf(acc[2], inv, b0.z), fmaf(acc[3], inv, b0.w));
        o.z = pack_bf2(fmaf(acc[4], inv, b1.x), fmaf(acc[5], inv, b1.y));
        o.w = pack_bf2(fmaf(acc[6], inv, b1.z), fmaf(acc[7], inv, b1.w));
        ((uint4*)out)[(size_t)n * 32 + c32] = o;
    }
}

// ---------------- layer-2 aggregation: one wave/node, 4 groups, 4-stage pipeline --------
__global__ __launch_bounds__(256) void k_agg2(const ushort* __restrict__ h2,
                                              const int* __restrict__ row_ptr,
                                              const float4* __restrict__ wm,
                                              const float* __restrict__ al_s,
                                              const float* __restrict__ al_d,
                                              const float* __restrict__ lE,
                                              const float* __restrict__ bias,
                                              ushort* __restrict__ out, int N) {
    int n = blockIdx.x * 4 + (threadIdx.x >> 6);
    if (n >= N) return;
    int lane = threadIdx.x & 63;
    int g = lane >> 4, c16 = lane & 15;
    bool hi = c16 >= 8;
    const uint4* h2u4 = (const uint4*)h2;
    float2 ad = *(const float2*)(al_d + 2 * (size_t)n);
    float2 as = *(const float2*)(al_s + 2 * (size_t)n);
    float wsA = __expf(lrelu(as.x + ad.x + lE[0]));
    float wsB = __expf(lrelu(as.y + ad.y + lE[1]));
    uint4 hs = h2u4[(size_t)n * 16 + c16];
    float wself = (g == 0) ? (hi ? wsB : wsA) : 0.f;
    float dsum = wself;
    float acc[8];
    {
        float2 t0 = unpack_bf2(hs.x), t1 = unpack_bf2(hs.y);
        float2 t2 = unpack_bf2(hs.z), t3 = unpack_bf2(hs.w);
        acc[0] = wself * t0.x; acc[1] = wself * t0.y;
        acc[2] = wself * t1.x; acc[3] = wself * t1.y;
        acc[4] = wself * t2.x; acc[5] = wself * t2.y;
        acc[6] = wself * t3.x; acc[7] = wself * t3.y;
    }
    int i0 = row_ptr[n];
    int cnt = row_ptr[n + 1] - i0;
    if (cnt > 0) {
        int last = cnt - 1;
        int nit = (cnt + 3) >> 2;
        int j0 = g;      float mkA = 1.f; if (j0 > last) { j0 = last; mkA = 0.f; }
        int j1 = 4 + g;  float mkB = 1.f; if (j1 > last) { j1 = last; mkB = 0.f; }
        int j2 = 8 + g;  float mkC = 1.f; if (j2 > last) { j2 = last; mkC = 0.f; }
        int j3 = 12 + g; float mkD = 1.f; if (j3 > last) { j3 = last; mkD = 0.f; }
        float4 meA = wm[i0 + j0];
        float4 meB = wm[i0 + j1];
        float4 meC = wm[i0 + j2];
        float4 meD = wm[i0 + j3];
        uint4 gvA = h2u4[(size_t)__float_as_int(meA.x) * 16 + c16];
        uint4 gvB = h2u4[(size_t)__float_as_int(meB.x) * 16 + c16];
        uint4 gvC = h2u4[(size_t)__float_as_int(meC.x) * 16 + c16];
        for (int it = 0; it < nit - 1; ++it) {
            uint4 gvD = h2u4[(size_t)__float_as_int(meD.x) * 16 + c16];
            int jn = 4 * (it + 4) + g;
            float mn = 1.f;
            if (jn > last) { jn = last; mn = 0.f; }
            float4 meE = wm[i0 + jn];
            float wg = (hi ? meA.z : meA.y) * mkA;
            dsum += wg;
            float2 u;
            u = unpack_bf2(gvA.x); acc[0] = fmaf(wg, u.x, acc[0]); acc[1] = fmaf(wg, u.y, acc[1]);
            u = unpack_bf2(gvA.y); acc[2] = fmaf(wg, u.x, acc[2]); acc[3] = fmaf(wg, u.y, acc[3]);
            u = unpack_bf2(gvA.z); acc[4] = fmaf(wg, u.x, acc[4]); acc[5] = fmaf(wg, u.y, acc[5]);
            u = unpack_bf2(gvA.w); acc[6] = fmaf(wg, u.x, acc[6]); acc[7] = fmaf(wg, u.y, acc[7]);
            meA = meB; meB = meC; meC = meD; meD = meE;
            gvA = gvB; gvB = gvC; gvC = gvD;
            mkA = mkB; mkB = mkC; mkC = mkD; mkD = mn;
        }
        float wg = (hi ? meA.z : meA.y) * mkA;
        dsum += wg;
        float2 u;
        u = unpack_bf2(gvA.x); acc[0] = fmaf(wg, u.x, acc[0]); acc[1] = fmaf(wg, u.y, acc[1]);
        u = unpack_bf2(gvA.y); acc[2] = fmaf(wg, u.x, acc[2]); acc[3] = fmaf(wg, u.y, acc[3]);
        u = unpack_bf2(gvA.z); acc[4] = fmaf(wg, u.x, acc[4]); acc[5] = fmaf(wg, u.y, acc[5]);
        u = unpack_bf2(gvA.w); acc[6] = fmaf(wg, u.x, acc[6]); acc[7] = fmaf(wg, u.y, acc[7]);
    }
#pragma unroll
    for (int k = 0; k < 8; ++k) {
        acc[k] += __shfl_xor(acc[k], 16);
        acc[k] += __shfl_xor(acc[k], 32);
    }
    dsum += __shfl_xor(dsum, 16);
    dsum += __shfl_xor(dsum, 32);
    if (g == 0) {
        float inv = 1.f / dsum;
        const float* bp = bias + c16 * 8;
        float4 b0 = *(const float4*)bp;
        float4 b1 = *(const float4*)(bp + 4);
        uint4 o;
        o.x = pack_bf2(fmaf(acc[0], inv, b0.x), fmaf(acc[1], inv, b0.y));
        o.y = pack_bf2(fmaf(acc[2], inv, b0.z), fmaf(acc[3], inv, b0.w));
        o.z = pack_bf2(fmaf(acc[4], inv, b1.x), fmaf(acc[5], inv, b1.y));
        o.w = pack_bf2(fmaf(acc[6], inv, b1.z), fmaf(acc[7], inv, b1.w));
        ((uint4*)out)[(size_t)n * 16 + c16] = o;
    }
}

// ---------------- GraphNorm column stats: uint4 streaming + LDS tree + few atomics ----------
template <int C4>
__global__ __launch_bounds__(256) void k_stats_bf(const ushort* __restrict__ x,
                                                  float* __restrict__ stats, int rows) {
    const int C = C4 * 8;
    const int RG = 256 / C4;
    int t = threadIdx.x;
    int c = t & (C4 - 1);
    int rg = t / C4;
    int rpb = (rows + gridDim.x - 1) / gridDim.x;
    int r0 = blockIdx.x * rpb;
    int r1 = r0 + rpb;
    if (r1 > rows) r1 = rows;
    const uint4* xu = (const uint4*)x;
    float s[8] = {0.f, 0.f, 0.f, 0.f, 0.f, 0.f, 0.f, 0.f};
    float q[8] = {0.f, 0.f, 0.f, 0.f, 0.f, 0.f, 0.f, 0.f};
    for (int r = r0 + rg; r < r1; r += RG) {
        uint4 v = xu[(size_t)r * C4 + c];
        float2 a0 = unpack_bf2(v.x), a1 = unpack_bf2(v.y);
        float2 a2 = unpack_bf2(v.z), a3 = unpack_bf2(v.w);
        s[0] += a0.x; q[0] = fmaf(a0.x, a0.x, q[0]);
        s[1] += a0.y; q[1] = fmaf(a0.y, a0.y, q[1]);
        s[2] += a1.x; q[2] = fmaf(a1.x, a1.x, q[2]);
        s[3] += a1.y; q[3] = fmaf(a1.y, a1.y, q[3]);
        s[4] += a2.x; q[4] = fmaf(a2.x, a2.x, q[4]);
        s[5] += a2.y; q[5] = fmaf(a2.y, a2.y, q[5]);
        s[6] += a3.x; q[6] = fmaf(a3.x, a3.x, q[6]);
        s[7] += a3.y; q[7] = fmaf(a3.y, a3.y, q[7]);
    }
    __shared__ float ls[256 * 16];
#pragma unroll
    for (int k = 0; k < 8; ++k) {
        ls[t * 16 + k] = s[k];
        ls[t * 16 + 8 + k] = q[k];
    }
    __syncthreads();
    if (t < C) {
        int cc = t >> 3, k = t & 7;
        float ssum = 0.f, qsum = 0.f;
#pragma unroll
        for (int g = 0; g < RG; ++g) {
            ssum += ls[(g * C4 + cc) * 16 + k];
            qsum += ls[(g * C4 + cc) * 16 + 8 + k];
        }
        atomicAdd(&stats[t], ssum);
        atomicAdd(&stats[C + t], qsum);
    }
}

// ---------------- MFMA GEMM2 + per-block coef from stats + fused layer-2 attn dots ----------
__global__ __launch_bounds__(256) void k_gemm2_mfma(const ushort* __restrict__ X,
                                                    const float* __restrict__ stats,
                                                    const float* __restrict__ gw,
                                                    const float* __restrict__ gb,
                                                    const float* __restrict__ gms,
                                                    const uint4* __restrict__ Bfrag,
                                                    const float* __restrict__ as2,
                                                    const float* __restrict__ ad2,
                                                    ushort* __restrict__ H2,
                                                    float* __restrict__ al_s,
                                                    float* __restrict__ al_d, int Nn) {
    __shared__ __align__(16) float ABs[512];
    {
        int t = threadIdx.x;
        float inv = 1.f / (float)Nn;
        float mean = stats[t] * inv;
        float cm = mean * gms[t];
        float var = stats[256 + t] * inv - 2.f * cm * mean + cm * cm;
        float A = gw[t] * rsqrtf(var + GEPS);
        ABs[t] = A;
        ABs[256 + t] = gb[t] - A * cm;
    }
    __syncthreads();
    int wave = threadIdx.x >> 6, lane = threadIdx.x & 63;
    int q = lane >> 4, m = lane & 15;
    int rowbase = blockIdx.x * 64 + wave * 16;
    int row = rowbase + m;
    bool valid = row < Nn;
    const uint4* xr4 = (const uint4*)((const unsigned int*)X + (size_t)row * 128);
    uint4 xa[8];
#pragma unroll
    for (int kk = 0; kk < 8; ++kk) {
        int k0 = kk * 32 + q * 8;
        xa[kk] = valid ? xr4[k0 >> 3] : make_uint4(0, 0, 0, 0);
    }
    union { short8 s; unsigned int u[4]; } af[8];
#pragma unroll
    for (int kk = 0; kk < 8; ++kk) {
        int k0 = kk * 32 + q * 8;
        float2 x01 = unpack_bf2(xa[kk].x);
        float2 x23 = unpack_bf2(xa[kk].y);
        float2 x45 = unpack_bf2(xa[kk].z);
        float2 x67 = unpack_bf2(xa[kk].w);
        float4 a0 = *(const float4*)(ABs + k0);
        float4 a1 = *(const float4*)(ABs + k0 + 4);
        float4 b0 = *(const float4*)(ABs + 256 + k0);
        float4 b1 = *(const float4*)(ABs + 256 + k0 + 4);
        float v0 = elu_fast(fmaf(a0.x, x01.x, b0.x));
        float v1 = elu_fast(fmaf(a0.y, x01.y, b0.y));
        float v2 = elu_fast(fmaf(a0.z, x23.x, b0.z));
        float v3 = elu_fast(fmaf(a0.w, x23.y, b0.w));
        float v4 = elu_fast(fmaf(a1.x, x45.x, b1.x));
        float v5 = elu_fast(fmaf(a1.y, x45.y, b1.y));
        float v6 = elu_fast(fmaf(a1.z, x67.x, b1.z));
        float v7 = elu_fast(fmaf(a1.w, x67.y, b1.w));
        af[kk].u[0] = pack_bf2(v0, v1);
        af[kk].u[1] = pack_bf2(v2, v3);
        af[kk].u[2] = pack_bf2(v4, v5);
        af[kk].u[3] = pack_bf2(v6, v7);
    }
    floatx4 acc[8];
#pragma unroll
    for (int c = 0; c < 8; ++c) acc[c] = (floatx4){0.f, 0.f, 0.f, 0.f};
#pragma unroll
    for (int kk = 0; kk < 8; ++kk) {
        const uint4* bpf = Bfrag + kk * 64 + lane;
#pragma unroll
        for (int c = 0; c < 8; ++c) {
            union { short8 s; uint4 u; } bf;
            bf.u = bpf[c * 8 * 64];
            acc[c] = __builtin_amdgcn_mfma_f32_16x16x32_bf16(af[kk].s, bf.s, acc[c], 0, 0, 0);
        }
    }
    float a_s[8], a_d[8];
#pragma unroll
    for (int c = 0; c < 8; ++c) {
        a_s[c] = as2[c * 16 + m];
        a_d[c] = ad2[c * 16 + m];
    }
#pragma unroll
    for (int r = 0; r < 4; ++r) {
        int orow = rowbase + q * 4 + r;
        bool vr = orow < Nn;
        ushort us[8];
        float s0 = 0.f, s1 = 0.f, d0 = 0.f, d1 = 0.f;
#pragma unroll
        for (int c = 0; c < 8; ++c) {
            us[c] = f2bf(acc[c][r]);
            float v = bf2f(us[c]);
            if (c < 4) {
                s0 = fmaf(v, a_s[c], s0);
                d0 = fmaf(v, a_d[c], d0);
            } else {
                s1 = fmaf(v, a_s[c], s1);
                d1 = fmaf(v, a_d[c], d1);
            }
        }
#pragma unroll
        for (int o = 1; o < 16; o <<= 1) {
            s0 += __shfl_xor(s0, o);
            s1 += __shfl_xor(s1, o);
            d0 += __shfl_xor(d0, o);
            d1 += __shfl_xor(d1, o);
        }
        if (vr) {
            ushort* op = H2 + (size_t)orow * 128 + m;
#pragma unroll
            for (int c = 0; c < 8; ++c) op[c * 16] = us[c];
            if (m == 0) {
                *(float2*)(al_s + 2 * (size_t)orow) = make_float2(s0, s1);
                *(float2*)(al_d + 2 * (size_t)orow) = make_float2(d0, d1);
            }
        }
    }
}

// ---------------- classifier: per-block coef from stats + fused GraphNorm+ELU ----------------
__global__ __launch_bounds__(256) void k_cls(const ushort* __restrict__ X,
                                             const float* __restrict__ stats,
                                             const float* __restrict__ gw,
                                             const float* __restrict__ gb,
                                             const float* __restrict__ gms,
                                             const float* __restrict__ Wc,
                                             const float* __restrict__ bc,
                                             float* __restrict__ out, int Nn) {
    __shared__ __align__(16) float ls[16 * 132];
    __shared__ __align__(16) float wT[13 * 132];
    __shared__ __align__(16) float ABs[256];
    __shared__ float bS[13];
    int t = threadIdx.x;
    int n0 = blockIdx.x * 16;
    if (t < 128) {
        float inv = 1.f / (float)Nn;
        float mean = stats[t] * inv;
        float cm = mean * gms[t];
        float var = stats[128 + t] * inv - 2.f * cm * mean + cm * cm;
        float A = gw[t] * rsqrtf(var + GEPS);
        ABs[t] = A;
        ABs[128 + t] = gb[t] - A * cm;
    }
    for (int i = t; i < 128 * 13; i += 256) {
        int k = i / 13, j = i - k * 13;
        wT[j * 132 + k] = Wc[i];
    }
    if (t < 13) bS[t] = bc[t];
    __syncthreads();
    const unsigned int* xu = (const unsigned int*)X;
    for (int idx = t; idx < 16 * 64; idx += 256) {
        int r = idx >> 6, ku = idx & 63;
        int row = n0 + r;
        float vx = 0.f, vy = 0.f;
        if (row < Nn) {
            float2 v = unpack_bf2(xu[(size_t)row * 64 + ku]);
            int k = 2 * ku;
            vx = elu_fast(fmaf(ABs[k], v.x, ABs[128 + k]));
            vy = elu_fast(fmaf(ABs[k + 1], v.y, ABs[128 + k + 1]));
        }
        ls[r * 132 + 2 * ku] = vx;
        ls[r * 132 + 2 * ku + 1] = vy;
    }
    __syncthreads();
    if (t < 208) {
        int r = t / 13, j = t - r * 13;
        int row = n0 + r;
        if (row < Nn) {
            float acc = bS[j];
            const float* lr = &ls[r * 132];
            const float* wr = &wT[j * 132];
#pragma unroll 8
            for (int k = 0; k < 128; k += 4) {
                float4 a = *(const float4*)&lr[k];
                float4 b = *(const float4*)&wr[k];
                acc = fmaf(a.x, b.x, fmaf(a.y, b.y, fmaf(a.z, b.z, fmaf(a.w, b.w, acc))));
            }
            out[(size_t)row * 13 + j] = acc;
        }
    }
}

extern "C" void kernel_launch(void* const* d_in, const int* in_sizes, int n_in, void* d_out,
                              int out_size, void* d_ws, size_t ws_size, hipStream_t stream) {
    const float* x = (const float*)d_in[0];
    const int* edge_index = (const int*)d_in[1];
    const float* edge_attr = (const float*)d_in[2];
    const float* W1 = (const float*)d_in[3];
    const float* We1 = (const float*)d_in[4];
    const float* as1 = (const float*)d_in[5];
    const float* ad1 = (const float*)d_in[6];
    const float* ae1 = (const float*)d_in[7];
    const float* b1 = (const float*)d_in[8];
    const float* gn1_w = (const float*)d_in[9];
    const float* gn1_b = (const float*)d_in[10];
    const float* gn1_ms = (const float*)d_in[11];
    const float* W2 = (const float*)d_in[12];
    const float* We2 = (const float*)d_in[13];
    const float* as2 = (const float*)d_in[14];
    const float* ad2 = (const float*)d_in[15];
    const float* ae2 = (const float*)d_in[16];
    const float* b2 = (const float*)d_in[17];
    const float* gn2_w = (const float*)d_in[18];
    const float* gn2_b = (const float*)d_in[19];
    const float* gn2_ms = (const float*)d_in[20];
    const float* Wc = (const float*)d_in[21];
    const float* bc = (const float*)d_in[22];

    const int N = in_sizes[0] / 3;
    const int E = in_sizes[1] / 2;
    const int* srcv = edge_index;
    const int* dstv = edge_index + E;

    // ---- workspace carve (256B-aligned, byte-based) ----
    char* w = (char*)d_ws;
    auto carveB = [&](size_t bytes) -> void* {
        void* p = (void*)w;
        w += ((bytes + 255) / 256) * 256;
        return p;
    };
    // zeroed region first:
    int* deg = (int*)carveB((size_t)N * 4);
    float* ea_sum = (float*)carveB(8);
    float* statsA = (float*)carveB(512 * 4);
    float* statsB = (float*)carveB(256 * 4);
    char* zero_end = w;
    // not zeroed:
    int* row_ptr = (int*)carveB((size_t)(N + 1) * 4);
    int* bsum = (int*)carveB(1024 * 4);
    float4* ed2 = (float4*)carveB((size_t)E * 16);
    uint4* wmp = (uint4*)carveB((size_t)E * 16);
    float4* wm2 = (float4*)wmp;  // layer-2 weights reuse (wmp dead after agg1)
    float* C1 = (float*)carveB(8 * 4);
    float* lE1 = (float*)carveB(4 * 4);
    float* C2 = (float*)carveB(4 * 4);
    float* lE2 = (float*)carveB(2 * 4);
    uint4* Bfrag = (uint4*)carveB(4096 * 16);
    float* al_s1 = (float*)carveB((size_t)N * 4 * 4);
    float* al_d1 = (float*)carveB((size_t)N * 4 * 4);
    float* al_s2 = (float*)carveB((size_t)N * 2 * 4);
    float* al_d2 = (float*)carveB((size_t)N * 2 * 4);
    ushort* h1b = (ushort*)carveB((size_t)N * 256 * 2);   // bf16 h1; later aliased by out2b
    ushort* h2b = (ushort*)carveB((size_t)N * 128 * 2);   // bf16 h2
    ushort* out1b = (ushort*)carveB((size_t)N * 256 * 2); // bf16 layer-1 output
    ushort* out2b = h1b;                                  // bf16 layer-2 output (h1b dead)

    hipMemsetAsync(deg, 0, (size_t)(zero_end - (char*)deg), stream);

    const int nb1 = (N + 1023) / 1024;
    const int ebl = (E + 255) / 256;

    k_pre<<<TBLK + 17 + 256, 256, 0, stream>>>(x, W1, as1, ad1, edge_attr, dstv, W2, We1, ae1,
                                               We2, ae2, h1b, al_s1, al_d1, ea_sum, deg, Bfrag,
                                               C1, C2, N, E);
    k_scan1<<<nb1, 1024, 0, stream>>>(deg, row_ptr, bsum, N);
    k_scan23<<<nb1, 1024, 0, stream>>>(row_ptr, bsum, ea_sum, C1, C2, lE1, lE2, N, E);
    k_scatfill<<<ebl, 256, 0, stream>>>(dstv, srcv, edge_attr, row_ptr, deg, al_s1, al_d1, C1,
                                        ed2, wmp, E);
    k_agg1<<<(N + 3) / 4, 256, 0, stream>>>(h1b, row_ptr, wmp, al_s1, al_d1, lE1, b1, out1b, N);
    k_stats_bf<32><<<256, 256, 0, stream>>>(out1b, statsA, N);
    k_gemm2_mfma<<<(N + 63) / 64, 256, 0, stream>>>(out1b, statsA, gn1_w, gn1_b, gn1_ms, Bfrag,
                                                    as2, ad2, h2b, al_s2, al_d2, N);
    k_fill2<<<ebl, 256, 0, stream>>>(ed2, al_s2, al_d2, C2, wm2, E);
    k_agg2<<<(N + 3) / 4, 256, 0, stream>>>(h2b, row_ptr, wm2, al_s2, al_d2, lE2, b2, out2b, N);
    k_stats_bf<16><<<256, 256, 0, stream>>>(out2b, statsB, N);
    k_cls<<<(N + 15) / 16, 256, 0, stream>>>(out2b, statsB, gn2_w, gn2_b, gn2_ms, Wc, bc,
                                             (float*)d_out, N);
}